// Round 1
// baseline (282.582 us; speedup 1.0000x reference)
//
#include <hip/hip_runtime.h>
#include <hip/hip_bf16.h>

typedef __attribute__((ext_vector_type(8))) short v8s;           // 8 x bf16 for MFMA A/B
typedef __attribute__((ext_vector_type(8))) unsigned short u16x8;
typedef __attribute__((ext_vector_type(4))) float v4f;           // MFMA C/D

#define MFMA16(a, b, c) __builtin_amdgcn_mfma_f32_16x16x32_bf16((a), (b), (c), 0, 0, 0)

__device__ __forceinline__ unsigned short f2bf(float f) {
  union { float f; unsigned u; } v; v.f = f;
  unsigned r = v.u + 0x7fffu + ((v.u >> 16) & 1u);   // RNE
  return (unsigned short)(r >> 16);
}

// ---------------- fp32 -> bf16 convert (weights) ----------------
__global__ __launch_bounds__(256) void cvt_kernel(const float* __restrict__ in,
                                                  unsigned short* __restrict__ out, int n4) {
  int i = blockIdx.x * 256 + threadIdx.x;
  if (i >= n4) return;
  float4 v = ((const float4*)in)[i];
  ushort4 o;
  o.x = f2bf(v.x); o.y = f2bf(v.y); o.z = f2bf(v.z); o.w = f2bf(v.w);
  ((ushort4*)out)[i] = o;
}

// ---------------- GroupNorm: one block per (b, group) ----------------
// group = 16 channels x 1024 = 16384 floats. fp32 stats, bf16 output.
__global__ __launch_bounds__(256) void gn_kernel(const float* __restrict__ x,
                                                 const float* __restrict__ gsc,
                                                 const float* __restrict__ gbi,
                                                 unsigned short* __restrict__ xn) {
  const int b = blockIdx.x >> 5, g = blockIdx.x & 31;
  const float* xp = x + ((size_t)b * 512 + g * 16) * 1024;
  unsigned short* op = xn + ((size_t)b * 512 + g * 16) * 1024;
  const float4* xp4 = (const float4*)xp;

  float s = 0.f, ss = 0.f;
  for (int i = threadIdx.x; i < 4096; i += 256) {
    float4 v = xp4[i];
    s  += (v.x + v.y) + (v.z + v.w);
    ss += (v.x * v.x + v.y * v.y) + (v.z * v.z + v.w * v.w);
  }
  #pragma unroll
  for (int d = 1; d < 64; d <<= 1) { s += __shfl_xor(s, d); ss += __shfl_xor(ss, d); }
  __shared__ float red[2][4];
  const int w = threadIdx.x >> 6;
  if ((threadIdx.x & 63) == 0) { red[0][w] = s; red[1][w] = ss; }
  __syncthreads();
  s  = red[0][0] + red[0][1] + red[0][2] + red[0][3];
  ss = red[1][0] + red[1][1] + red[1][2] + red[1][3];
  const float mu  = s * (1.f / 16384.f);
  const float var = ss * (1.f / 16384.f) - mu * mu;
  const float rs  = rsqrtf(var + 1e-5f);

  for (int i = threadIdx.x; i < 4096; i += 256) {
    float4 v = xp4[i];
    const int c = g * 16 + (i >> 8);           // (i*4)/1024
    const float sc = gsc[c] * rs;
    const float bi = gbi[c] - mu * sc;
    ushort4 o;
    o.x = f2bf(v.x * sc + bi); o.y = f2bf(v.y * sc + bi);
    o.z = f2bf(v.z * sc + bi); o.w = f2bf(v.w * sc + bi);
    ((ushort4*)op)[i] = o;
  }
}

// ---------------- bf16 MFMA GEMM: D[b,m,n] = A[m,:]·B[b,:,n] + bias[m] (+resid) ----
// Tile 64(M) x 64(N), BK=32, 256 threads = 4 waves in 2x2. N fixed = 1024.
template <int M, int K, bool RESID>
__global__ __launch_bounds__(256) void gemm_kernel(
    const unsigned short* __restrict__ A,   // M x K bf16
    const unsigned short* __restrict__ B,   // batch x K x 1024 bf16
    const float* __restrict__ bias,         // M
    const float* __restrict__ resid,        // batch x M x 1024 f32 (RESID)
    float* __restrict__ outf,               // RESID: f32 out
    unsigned short* __restrict__ outb) {    // !RESID: bf16 out
  const int n0 = blockIdx.x * 64;
  const int m0 = blockIdx.y * 64;
  const int b  = blockIdx.z;
  const unsigned short* Bp = B + (size_t)b * K * 1024;

  __shared__ __align__(16) unsigned short As[64][32];   // [m][k]
  __shared__ __align__(16) unsigned short Bs[64][32];   // [n][k] (transposed)

  const int tid = threadIdx.x, lane = tid & 63, w = tid >> 6;
  const int quad = lane >> 4, l15 = lane & 15;
  const int wm = (w >> 1) * 32, wn = (w & 1) * 32;
  const int ar = tid >> 2, ac = (tid & 3) * 8;     // A stage: row, col8
  const int bk = tid >> 3, bn = (tid & 7) * 8;     // B stage: krow, ncol8

  v4f acc[2][2];
  #pragma unroll
  for (int i = 0; i < 2; ++i)
    #pragma unroll
    for (int j = 0; j < 2; ++j) acc[i][j] = (v4f){0.f, 0.f, 0.f, 0.f};

  for (int kk = 0; kk < K; kk += 32) {
    uint4 av = *(const uint4*)(A + (size_t)(m0 + ar) * K + kk + ac);
    u16x8 bv = *(const u16x8*)(Bp + (size_t)(kk + bk) * 1024 + n0 + bn);
    __syncthreads();                       // prior iter's LDS reads done
    *(uint4*)&As[ar][ac] = av;
    #pragma unroll
    for (int j = 0; j < 8; ++j) Bs[bn + j][bk] = bv[j];
    __syncthreads();
    v8s af0 = *(const v8s*)&As[wm + l15][quad * 8];
    v8s af1 = *(const v8s*)&As[wm + 16 + l15][quad * 8];
    v8s bf0 = *(const v8s*)&Bs[wn + l15][quad * 8];
    v8s bf1 = *(const v8s*)&Bs[wn + 16 + l15][quad * 8];
    acc[0][0] = MFMA16(af0, bf0, acc[0][0]);
    acc[0][1] = MFMA16(af0, bf1, acc[0][1]);
    acc[1][0] = MFMA16(af1, bf0, acc[1][0]);
    acc[1][1] = MFMA16(af1, bf1, acc[1][1]);
  }

  #pragma unroll
  for (int mt = 0; mt < 2; ++mt)
    #pragma unroll
    for (int nt = 0; nt < 2; ++nt)
      #pragma unroll
      for (int r = 0; r < 4; ++r) {
        const int mg = m0 + wm + mt * 16 + quad * 4 + r;
        const int ng = n0 + wn + nt * 16 + l15;
        const float v = acc[mt][nt][r] + bias[mg];
        const size_t idx = ((size_t)b * M + mg) * 1024 + ng;
        if (RESID) outf[idx] = resid[idx] + v;
        else       outb[idx] = f2bf(v);
      }
}

// ---------------- Flash attention: one block = one head x 64-query tile ----------
// qkv layout: [b][1536][1024] bf16; head h rows h*192 (+0 q, +64 k, +128 v).
__global__ __launch_bounds__(256) void attn_kernel(const unsigned short* __restrict__ qkv,
                                                   unsigned short* __restrict__ aout) {
  const int bh = blockIdx.y, b = bh >> 3, h = bh & 7;
  const int t0 = blockIdx.x * 64;
  const unsigned short* qb = qkv + ((size_t)b * 1536 + h * 192) * 1024;
  const unsigned short* kb = qb + 64 * 1024;
  const unsigned short* vb = qb + 128 * 1024;

  __shared__ __align__(16) unsigned short Qs[64][64];     // [t][c]
  __shared__ __align__(16) unsigned short Ks[32][64];     // [s][c]
  __shared__ __align__(16) unsigned short Vs[64][32];     // [c][s]
  __shared__ __align__(16) unsigned short Ps[4][16][32];  // per wave [t][s]

  const int tid = threadIdx.x, w = tid >> 6, lane = tid & 63;
  const int quad = lane >> 4, l15 = lane & 15;

  // stage Q transposed: Qs[t][c] = q[c][t0+t]
  {
    const int c = tid >> 3, t8 = (tid & 7) * 8;
    for (int cc = c; cc < 64; cc += 32) {
      u16x8 v = *(const u16x8*)(qb + (size_t)cc * 1024 + t0 + t8);
      #pragma unroll
      for (int j = 0; j < 8; ++j) Qs[t8 + j][cc] = v[j];
    }
  }
  __syncthreads();

  v8s qf[2];
  qf[0] = *(const v8s*)&Qs[w * 16 + l15][quad * 8];
  qf[1] = *(const v8s*)&Qs[w * 16 + l15][32 + quad * 8];

  v4f o[4];
  #pragma unroll
  for (int i = 0; i < 4; ++i) o[i] = (v4f){0.f, 0.f, 0.f, 0.f};
  float mrow[4] = {-1e30f, -1e30f, -1e30f, -1e30f};
  float lrow[4] = {0.f, 0.f, 0.f, 0.f};
  const float c2 = 0.125f * 1.44269504088896f;   // scale^2 * log2(e)

  const int kc = tid >> 2, ks8 = (tid & 3) * 8;  // K/V stage mapping

  for (int s0 = 0; s0 < 1024; s0 += 32) {
    __syncthreads();                              // prev iter's Ks/Vs reads done
    {
      u16x8 kv = *(const u16x8*)(kb + (size_t)kc * 1024 + s0 + ks8);
      #pragma unroll
      for (int j = 0; j < 8; ++j) Ks[ks8 + j][kc] = kv[j];
      uint4 vv = *(const uint4*)(vb + (size_t)kc * 1024 + s0 + ks8);
      *(uint4*)&Vs[kc][ks8] = vv;
    }
    __syncthreads();

    // S(16x32) = Q(16x64) · K^T ; s-halves in sa0 (s0..15) / sa1 (s16..31)
    v4f sa0 = (v4f){0.f, 0.f, 0.f, 0.f}, sa1 = (v4f){0.f, 0.f, 0.f, 0.f};
    #pragma unroll
    for (int kst = 0; kst < 2; ++kst) {
      v8s b0 = *(const v8s*)&Ks[l15][kst * 32 + quad * 8];
      v8s b1 = *(const v8s*)&Ks[16 + l15][kst * 32 + quad * 8];
      sa0 = MFMA16(qf[kst], b0, sa0);
      sa1 = MFMA16(qf[kst], b1, sa1);
    }

    // online softmax (log2 domain), rows r -> t = w*16 + quad*4 + r
    float al[4];
    #pragma unroll
    for (int r = 0; r < 4; ++r) {
      const float v0 = sa0[r] * c2, v1 = sa1[r] * c2;
      float mx = fmaxf(v0, v1);
      mx = fmaxf(mx, __shfl_xor(mx, 1));
      mx = fmaxf(mx, __shfl_xor(mx, 2));
      mx = fmaxf(mx, __shfl_xor(mx, 4));
      mx = fmaxf(mx, __shfl_xor(mx, 8));
      const float mn = fmaxf(mrow[r], mx);
      const float a = exp2f(mrow[r] - mn);
      const float p0 = exp2f(v0 - mn), p1 = exp2f(v1 - mn);
      float rsum = p0 + p1;
      rsum += __shfl_xor(rsum, 1);
      rsum += __shfl_xor(rsum, 2);
      rsum += __shfl_xor(rsum, 4);
      rsum += __shfl_xor(rsum, 8);
      lrow[r] = lrow[r] * a + rsum;
      mrow[r] = mn;
      al[r] = a;
      Ps[w][quad * 4 + r][l15]      = f2bf(p0);
      Ps[w][quad * 4 + r][16 + l15] = f2bf(p1);
    }
    #pragma unroll
    for (int nc = 0; nc < 4; ++nc)
      #pragma unroll
      for (int r = 0; r < 4; ++r) o[nc][r] *= al[r];

    __syncthreads();                               // P write -> A-frag read
    // O(16x64) += P(16x32) · V^T  (A-frag from Ps, B-frag from Vs[c][s])
    v8s pa = *(const v8s*)&Ps[w][l15][quad * 8];
    #pragma unroll
    for (int nc = 0; nc < 4; ++nc) {
      v8s vbv = *(const v8s*)&Vs[nc * 16 + l15][quad * 8];
      o[nc] = MFMA16(pa, vbv, o[nc]);
    }
  }

  // write a[b][h*64+c][t0+t] = O[t][c]/l[t]
  #pragma unroll
  for (int nc = 0; nc < 4; ++nc) {
    const int c = nc * 16 + l15;
    unsigned short* op = aout + ((size_t)b * 512 + h * 64 + c) * 1024 + t0 + w * 16 + quad * 4;
    ushort4 st;
    st.x = f2bf(o[nc][0] / lrow[0]);
    st.y = f2bf(o[nc][1] / lrow[1]);
    st.z = f2bf(o[nc][2] / lrow[2]);
    st.w = f2bf(o[nc][3] / lrow[3]);
    *(ushort4*)op = st;
  }
}

extern "C" void kernel_launch(void* const* d_in, const int* in_sizes, int n_in,
                              void* d_out, int out_size, void* d_ws, size_t ws_size,
                              hipStream_t stream) {
  const float* x    = (const float*)d_in[0];
  const float* gsc  = (const float*)d_in[1];
  const float* gbi  = (const float*)d_in[2];
  const float* qkvw = (const float*)d_in[3];
  const float* qkvb = (const float*)d_in[4];
  const float* pjw  = (const float*)d_in[5];
  const float* pjb  = (const float*)d_in[6];
  float* out = (float*)d_out;

  unsigned short* ws   = (unsigned short*)d_ws;
  unsigned short* xn   = ws;                  // 8*512*1024        = 4194304
  unsigned short* qw   = xn + 4194304;        // 1536*512          =  786432
  unsigned short* pw   = qw + 786432;         // 512*512           =  262144
  unsigned short* qkvo = pw + 262144;         // 8*1536*1024       = 12582912
  unsigned short* aw   = qkvo + 12582912;     // 8*512*1024        = 4194304
  // total 22,020,096 ushorts = 44 MB of d_ws

  cvt_kernel<<<dim3(768), dim3(256), 0, stream>>>(qkvw, qw, 196608);
  cvt_kernel<<<dim3(256), dim3(256), 0, stream>>>(pjw, pw, 65536);
  gn_kernel<<<dim3(256), dim3(256), 0, stream>>>(x, gsc, gbi, xn);
  gemm_kernel<1536, 512, false><<<dim3(16, 24, 8), dim3(256), 0, stream>>>(
      qw, xn, qkvb, (const float*)nullptr, (float*)nullptr, qkvo);
  attn_kernel<<<dim3(16, 64), dim3(256), 0, stream>>>(qkvo, aw);
  gemm_kernel<512, 512, true><<<dim3(16, 8, 8), dim3(256), 0, stream>>>(
      pw, aw, pjb, x, out, (unsigned short*)nullptr);
}

// Round 2
// 177.490 us; speedup vs baseline: 1.5921x; 1.5921x over previous
//
#include <hip/hip_runtime.h>
#include <hip/hip_bf16.h>

typedef __attribute__((ext_vector_type(8))) short v8s;            // 8 x bf16 (4 VGPRs) MFMA A/B
typedef __attribute__((ext_vector_type(8))) unsigned short u16x8;
typedef __attribute__((ext_vector_type(4))) float v4f;            // MFMA C/D

#define MFMA16(a, b, c) __builtin_amdgcn_mfma_f32_16x16x32_bf16((a), (b), (c), 0, 0, 0)

// async global->LDS, 16B per lane; LDS dest = wave-uniform base + lane*16
#define GLL16(g, l)                                                        \
  __builtin_amdgcn_global_load_lds(                                        \
      (const __attribute__((address_space(1))) unsigned int*)(g),          \
      (__attribute__((address_space(3))) unsigned int*)(l), 16, 0, 0)

#if __has_builtin(__builtin_amdgcn_exp2f)
#define EXP2F(x) __builtin_amdgcn_exp2f(x)
#else
#define EXP2F(x) exp2f(x)
#endif

__device__ __forceinline__ unsigned short f2bf(float f) {
  union { float f; unsigned u; } v; v.f = f;
  unsigned r = v.u + 0x7fffu + ((v.u >> 16) & 1u);   // RNE
  return (unsigned short)(r >> 16);
}
// truncating pack of two f32 -> bf16x2 (lo in low half)
__device__ __forceinline__ unsigned packbf2(float lo, float hi) {
  union { float f; unsigned u; } a, b; a.f = lo; b.f = hi;
  return (a.u >> 16) | (b.u & 0xffff0000u);
}

// ---------------- fp32 -> bf16 convert (weights) ----------------
__global__ __launch_bounds__(256) void cvt_kernel(const float* __restrict__ in,
                                                  unsigned short* __restrict__ out, int n4) {
  int i = blockIdx.x * 256 + threadIdx.x;
  if (i >= n4) return;
  float4 v = ((const float4*)in)[i];
  ushort4 o;
  o.x = f2bf(v.x); o.y = f2bf(v.y); o.z = f2bf(v.z); o.w = f2bf(v.w);
  ((ushort4*)out)[i] = o;
}

// ---------------- GroupNorm: one block per (b, group); bf16 out [c][l] ----------------
__global__ __launch_bounds__(256) void gn_kernel(const float* __restrict__ x,
                                                 const float* __restrict__ gsc,
                                                 const float* __restrict__ gbi,
                                                 unsigned short* __restrict__ xn) {
  const int b = blockIdx.x >> 5, g = blockIdx.x & 31;
  const float* xp = x + ((size_t)b * 512 + g * 16) * 1024;
  unsigned short* op = xn + ((size_t)b * 512 + g * 16) * 1024;
  const float4* xp4 = (const float4*)xp;

  float s = 0.f, ss = 0.f;
  for (int i = threadIdx.x; i < 4096; i += 256) {
    float4 v = xp4[i];
    s  += (v.x + v.y) + (v.z + v.w);
    ss += (v.x * v.x + v.y * v.y) + (v.z * v.z + v.w * v.w);
  }
  #pragma unroll
  for (int d = 1; d < 64; d <<= 1) { s += __shfl_xor(s, d); ss += __shfl_xor(ss, d); }
  __shared__ float red[2][4];
  const int w = threadIdx.x >> 6;
  if ((threadIdx.x & 63) == 0) { red[0][w] = s; red[1][w] = ss; }
  __syncthreads();
  s  = red[0][0] + red[0][1] + red[0][2] + red[0][3];
  ss = red[1][0] + red[1][1] + red[1][2] + red[1][3];
  const float mu  = s * (1.f / 16384.f);
  const float var = ss * (1.f / 16384.f) - mu * mu;
  const float rs  = rsqrtf(var + 1e-5f);

  for (int i = threadIdx.x; i < 4096; i += 256) {
    float4 v = xp4[i];
    const int c = g * 16 + (i >> 8);
    const float sc = gsc[c] * rs;
    const float bi = gbi[c] - mu * sc;
    ushort4 o;
    o.x = f2bf(v.x * sc + bi); o.y = f2bf(v.y * sc + bi);
    o.z = f2bf(v.z * sc + bi); o.w = f2bf(v.w * sc + bi);
    ((ushort4*)op)[i] = o;
  }
}

// ---------------- bf16 transpose: xn [b][512][1024] -> xnT [b][1024][512] ----------------
// 64x64 tiles through padded fp32-slot LDS (conflict-free both phases).
__global__ __launch_bounds__(256) void trans_kernel(const unsigned short* __restrict__ src,
                                                    unsigned short* __restrict__ dst) {
  const int b = blockIdx.z, l0 = blockIdx.x * 64, r0 = blockIdx.y * 64;
  const unsigned short* sp = src + (size_t)b * 512 * 1024;
  unsigned short* dp = dst + (size_t)b * 1024 * 512;
  __shared__ unsigned T[64][65];
  const int tid = threadIdx.x;
  const int rr = tid >> 3, c8 = (tid & 7) * 8;
  #pragma unroll
  for (int sw = 0; sw < 2; ++sw) {
    u16x8 v = *(const u16x8*)(sp + (size_t)(r0 + sw * 32 + rr) * 1024 + l0 + c8);
    #pragma unroll
    for (int j = 0; j < 8; ++j) T[sw * 32 + rr][c8 + j] = v[j];
  }
  __syncthreads();
  #pragma unroll
  for (int sw = 0; sw < 2; ++sw) {
    const int ll = sw * 32 + rr;
    u16x8 o;
    #pragma unroll
    for (int j = 0; j < 8; ++j) o[j] = (unsigned short)T[c8 + j][ll];
    *(u16x8*)(dp + (size_t)(l0 + ll) * 512 + r0 + c8) = o;
  }
}

// ---------------- 128x128 MFMA GEMM, BK=32, global_load_lds staging ----------------
// A: [M][512] bf16 (row-major, k contiguous). BT: [batch][1024][512] bf16 ([n][k]).
// QKV=true: split epilogue -> qT/kT [bh][l][64] (q pre-scaled), v [bh][64][1024].
// QKV=false: proj epilogue -> out f32 = resid + acc + bias.
template <bool QKV>
__global__ __launch_bounds__(256) void gemm_kernel(
    const unsigned short* __restrict__ A,
    const unsigned short* __restrict__ BT,
    const float* __restrict__ bias,
    const float* __restrict__ xres,
    float* __restrict__ outf,
    unsigned short* __restrict__ qT,
    unsigned short* __restrict__ kT,
    unsigned short* __restrict__ vO) {
  constexpr int K = 512;
  const int n0 = blockIdx.x * 128, m0 = blockIdx.y * 128, b = blockIdx.z;
  const unsigned short* Bp = BT + (size_t)b * 1024 * K;

  __shared__ __align__(16) unsigned short As[128][32];
  __shared__ __align__(16) unsigned short Bs[128][32];

  const int tid = threadIdx.x, lane = tid & 63, w = tid >> 6;
  const int quad = lane >> 4, l15 = lane & 15;
  const int wm = (w >> 1) * 64, wn = (w & 1) * 64;
  const int srow = lane >> 2, scol8 = (lane & 3) * 8;

  v4f acc[4][4];
  #pragma unroll
  for (int i = 0; i < 4; ++i)
    #pragma unroll
    for (int j = 0; j < 4; ++j) acc[i][j] = (v4f){0.f, 0.f, 0.f, 0.f};

  for (int kk = 0; kk < K; kk += 32) {
    __syncthreads();
    #pragma unroll
    for (int jj = 0; jj < 4; ++jj) {
      const int job = w * 4 + jj;          // 0..7 = A segs, 8..15 = B segs
      if (job < 8) {
        GLL16(A + (size_t)(m0 + job * 16 + srow) * K + kk + scol8, &As[job * 16][0]);
      } else {
        const int j2 = job - 8;
        GLL16(Bp + (size_t)(n0 + j2 * 16 + srow) * K + kk + scol8, &Bs[j2 * 16][0]);
      }
    }
    __syncthreads();
    v8s af[4], bf[4];
    #pragma unroll
    for (int mt = 0; mt < 4; ++mt) af[mt] = *(const v8s*)&As[wm + mt * 16 + l15][quad * 8];
    #pragma unroll
    for (int nt = 0; nt < 4; ++nt) bf[nt] = *(const v8s*)&Bs[wn + nt * 16 + l15][quad * 8];
    #pragma unroll
    for (int mt = 0; mt < 4; ++mt)
      #pragma unroll
      for (int nt = 0; nt < 4; ++nt)
        acc[mt][nt] = MFMA16(af[mt], bf[nt], acc[mt][nt]);
  }

  if (QKV) {
    const int bh8 = b * 8;
    const float cs = 0.18033688011112042f;   // 0.125 * log2(e), folded into q
    #pragma unroll
    for (int mt = 0; mt < 4; ++mt) {
      const int m4 = m0 + wm + mt * 16 + quad * 4;   // multiple of 4
      const int h = m4 / 192;
      const int rr = m4 - h * 192;
      const int part = rr >> 6;                      // 0=q 1=k 2=v
      const int ch = rr & 63;                        // multiple of 4
      const float b0 = bias[m4], b1 = bias[m4 + 1], b2 = bias[m4 + 2], b3 = bias[m4 + 3];
      #pragma unroll
      for (int nt = 0; nt < 4; ++nt) {
        const int n = n0 + wn + nt * 16 + l15;
        v4f a = acc[mt][nt];
        const float v0 = a[0] + b0, v1 = a[1] + b1, v2 = a[2] + b2, v3 = a[3] + b3;
        if (part == 0) {
          ushort4 st4;
          st4.x = f2bf(v0 * cs); st4.y = f2bf(v1 * cs);
          st4.z = f2bf(v2 * cs); st4.w = f2bf(v3 * cs);
          *(ushort4*)(qT + ((size_t)(bh8 + h) * 1024 + n) * 64 + ch) = st4;
        } else if (part == 1) {
          ushort4 st4;
          st4.x = f2bf(v0); st4.y = f2bf(v1); st4.z = f2bf(v2); st4.w = f2bf(v3);
          *(ushort4*)(kT + ((size_t)(bh8 + h) * 1024 + n) * 64 + ch) = st4;
        } else {
          unsigned short* dp = vO + ((size_t)(bh8 + h) * 64 + ch) * 1024 + n;
          dp[0] = f2bf(v0); dp[1024] = f2bf(v1); dp[2048] = f2bf(v2); dp[3072] = f2bf(v3);
        }
      }
    }
  } else {
    #pragma unroll
    for (int mt = 0; mt < 4; ++mt) {
      const int m4 = m0 + wm + mt * 16 + quad * 4;
      const float b0 = bias[m4], b1 = bias[m4 + 1], b2 = bias[m4 + 2], b3 = bias[m4 + 3];
      #pragma unroll
      for (int nt = 0; nt < 4; ++nt) {
        const int n = n0 + wn + nt * 16 + l15;
        const size_t i0 = ((size_t)b * 512 + m4) * 1024 + n;
        outf[i0]        = xres[i0]        + acc[mt][nt][0] + b0;
        outf[i0 + 1024] = xres[i0 + 1024] + acc[mt][nt][1] + b1;
        outf[i0 + 2048] = xres[i0 + 2048] + acc[mt][nt][2] + b2;
        outf[i0 + 3072] = xres[i0 + 3072] + acc[mt][nt][3] + b3;
      }
    }
  }
}

// ---------------- Flash attention, S^T formulation, no in-kernel transposes --------
// qT/kT: [bh][1024][64] bf16 (q pre-scaled by 0.125*log2e); v: [bh][64][1024] bf16.
// Block = (64-query tile, bh); 4 waves, wave w owns queries t0+w*16..+15.
__global__ __launch_bounds__(256) void attn_kernel(const unsigned short* __restrict__ qT,
                                                   const unsigned short* __restrict__ kT,
                                                   const unsigned short* __restrict__ vv,
                                                   unsigned short* __restrict__ aT) {
  const int bh = blockIdx.y;
  const int t0 = blockIdx.x * 64;
  const unsigned short* qb = qT + (size_t)bh * 1024 * 64;
  const unsigned short* kb = kT + (size_t)bh * 1024 * 64;
  const unsigned short* vb = vv + (size_t)bh * 64 * 1024;

  __shared__ __align__(16) unsigned short Qs[2][64][32];   // [c-half][t][c32]
  __shared__ __align__(16) unsigned short Ks[2][64][32];   // [c-half][s][c32]
  __shared__ __align__(16) unsigned short Vs[2][64][32];   // [s-half][c][s32]

  const int tid = threadIdx.x, w = tid >> 6, lane = tid & 63;
  const int quad = lane >> 4, l15 = lane & 15;
  const int srow = lane >> 2, scol8 = (lane & 3) * 8;

  // stage Q (8 jobs, 2 per wave)
  #pragma unroll
  for (int jj = 0; jj < 2; ++jj) {
    const int job = w * 2 + jj, kst = job >> 2, seg = job & 3;
    GLL16(qb + (size_t)(t0 + seg * 16 + srow) * 64 + kst * 32 + scol8, &Qs[kst][seg * 16][0]);
  }
  __syncthreads();
  const v8s qf0 = *(const v8s*)&Qs[0][w * 16 + l15][quad * 8];
  const v8s qf1 = *(const v8s*)&Qs[1][w * 16 + l15][quad * 8];

  v4f o[4];
  #pragma unroll
  for (int i = 0; i < 4; ++i) o[i] = (v4f){0.f, 0.f, 0.f, 0.f};
  float m_s = -1e30f, l_s = 0.f;
  // bpermute source lanes for the S^T(C-layout) -> A-frag quad redistribution
  const int sl0 = ((((2 * quad) & 3) << 4) | l15);
  const int sl1 = ((((2 * quad + 1) & 3) << 4) | l15);

  for (int s0 = 0; s0 < 1024; s0 += 64) {
    __syncthreads();                       // prior iter's K/V reads complete
    #pragma unroll
    for (int jj = 0; jj < 4; ++jj) {
      const int job = w * 4 + jj;          // 0..7 = K segs, 8..15 = V segs
      if (job < 8) {
        const int kst = job >> 2, seg = job & 3;
        GLL16(kb + (size_t)(s0 + seg * 16 + srow) * 64 + kst * 32 + scol8,
              &Ks[kst][seg * 16][0]);
      } else {
        const int j2 = job - 8, kst = j2 >> 2, seg = j2 & 3;
        GLL16(vb + (size_t)(seg * 16 + srow) * 1024 + s0 + kst * 32 + scol8,
              &Vs[kst][seg * 16][0]);
      }
    }
    __syncthreads();                       // staging drained at barrier

    // S^T(64s x 16t) = K * Q^T ; sa[st]: rows s = st*16 + quad*4 + r, col t = l15
    v4f sa[4];
    #pragma unroll
    for (int st = 0; st < 4; ++st) {
      v8s kf0 = *(const v8s*)&Ks[0][st * 16 + l15][quad * 8];
      v8s kf1 = *(const v8s*)&Ks[1][st * 16 + l15][quad * 8];
      v4f z = (v4f){0.f, 0.f, 0.f, 0.f};
      z = MFMA16(kf0, qf0, z);
      sa[st] = MFMA16(kf1, qf1, z);
    }

    // online softmax in log2 domain (scale folded into q)
    float mx = -1e30f;
    #pragma unroll
    for (int st = 0; st < 4; ++st)
      #pragma unroll
      for (int r = 0; r < 4; ++r) mx = fmaxf(mx, sa[st][r]);
    mx = fmaxf(mx, __shfl_xor(mx, 16));
    mx = fmaxf(mx, __shfl_xor(mx, 32));
    const float mn = fmaxf(m_s, mx);
    const float alpha = EXP2F(m_s - mn);
    float p[4][4], rsum = 0.f;
    #pragma unroll
    for (int st = 0; st < 4; ++st)
      #pragma unroll
      for (int r = 0; r < 4; ++r) { p[st][r] = EXP2F(sa[st][r] - mn); rsum += p[st][r]; }
    rsum += __shfl_xor(rsum, 16);
    rsum += __shfl_xor(rsum, 32);
    l_s = l_s * alpha + rsum;
    m_s = mn;

    // rescale O: alpha lives at lane l15==t; O rows are t = quad*4 + r
    float alq[4];
    #pragma unroll
    for (int r = 0; r < 4; ++r) alq[r] = __shfl(alpha, quad * 4 + r);
    #pragma unroll
    for (int nc = 0; nc < 4; ++nc)
      #pragma unroll
      for (int r = 0; r < 4; ++r) o[nc][r] *= alq[r];

    // pack P pairs (bf16x2), then redistribute across quads into A-frag layout
    unsigned pk[4][2];
    #pragma unroll
    for (int st = 0; st < 4; ++st) {
      pk[st][0] = packbf2(p[st][0], p[st][1]);
      pk[st][1] = packbf2(p[st][2], p[st][3]);
    }
    union { v8s v; unsigned u[4]; } pa0, pa1;
    #pragma unroll
    for (int e = 0; e < 4; ++e) {
      const int sl = (e >> 1) ? sl1 : sl0;
      unsigned lo0 = __shfl(pk[0][e & 1], sl);
      unsigned hi0 = __shfl(pk[1][e & 1], sl);
      pa0.u[e] = (quad < 2) ? lo0 : hi0;
      unsigned lo1 = __shfl(pk[2][e & 1], sl);
      unsigned hi1 = __shfl(pk[3][e & 1], sl);
      pa1.u[e] = (quad < 2) ? lo1 : hi1;
    }

    // O(16t x 64c) += P * V^T
    #pragma unroll
    for (int nc = 0; nc < 4; ++nc) {
      v8s vf0 = *(const v8s*)&Vs[0][nc * 16 + l15][quad * 8];
      v8s vf1 = *(const v8s*)&Vs[1][nc * 16 + l15][quad * 8];
      o[nc] = MFMA16(pa0.v, vf0, o[nc]);
      o[nc] = MFMA16(pa1.v, vf1, o[nc]);
    }
  }

  // write aT[b][t][h*64+c] = O[t][c] / l(t)
  const int b = bh >> 3, h = bh & 7;
  float rl[4];
  #pragma unroll
  for (int r = 0; r < 4; ++r) rl[r] = 1.0f / __shfl(l_s, quad * 4 + r);
  #pragma unroll
  for (int nc = 0; nc < 4; ++nc)
    #pragma unroll
    for (int r = 0; r < 4; ++r) {
      aT[((size_t)b * 1024 + t0 + w * 16 + quad * 4 + r) * 512 + h * 64 + nc * 16 + l15] =
          f2bf(o[nc][r] * rl[r]);
    }
}

extern "C" void kernel_launch(void* const* d_in, const int* in_sizes, int n_in,
                              void* d_out, int out_size, void* d_ws, size_t ws_size,
                              hipStream_t stream) {
  const float* x    = (const float*)d_in[0];
  const float* gsc  = (const float*)d_in[1];
  const float* gbi  = (const float*)d_in[2];
  const float* qkvw = (const float*)d_in[3];
  const float* qkvb = (const float*)d_in[4];
  const float* pjw  = (const float*)d_in[5];
  const float* pjb  = (const float*)d_in[6];
  float* out = (float*)d_out;

  unsigned short* ws  = (unsigned short*)d_ws;
  unsigned short* qw  = ws;                   //  786432  qkv weights bf16
  unsigned short* pw  = qw + 786432;          //  262144  proj weights bf16
  unsigned short* xn  = pw + 262144;          // 4194304  gn out [b][c][l]
  unsigned short* xnT = xn + 4194304;         // 4194304  [b][l][c]
  unsigned short* qT  = xnT + 4194304;        // 4194304  [bh][l][64]
  unsigned short* kT  = qT + 4194304;         // 4194304  [bh][l][64]
  unsigned short* vv  = kT + 4194304;         // 4194304  [bh][64][l]
  unsigned short* aT  = xn;                   // alias (xn dead after transpose)
  // total 22,020,096 shorts = 44.04 MB (same footprint as round 1)

  cvt_kernel<<<dim3(768), dim3(256), 0, stream>>>(qkvw, qw, 196608);
  cvt_kernel<<<dim3(256), dim3(256), 0, stream>>>(pjw, pw, 65536);
  gn_kernel<<<dim3(256), dim3(256), 0, stream>>>(x, gsc, gbi, xn);
  trans_kernel<<<dim3(16, 8, 8), dim3(256), 0, stream>>>(xn, xnT);
  gemm_kernel<true><<<dim3(8, 12, 8), dim3(256), 0, stream>>>(
      qw, xnT, qkvb, nullptr, nullptr, qT, kT, vv);
  attn_kernel<<<dim3(16, 64), dim3(256), 0, stream>>>(qT, kT, vv, aT);
  gemm_kernel<false><<<dim3(8, 4, 8), dim3(256), 0, stream>>>(
      pw, aT, pjb, x, out, nullptr, nullptr, nullptr);
}

// Round 3
// 172.433 us; speedup vs baseline: 1.6388x; 1.0293x over previous
//
#include <hip/hip_runtime.h>
#include <hip/hip_bf16.h>

typedef __attribute__((ext_vector_type(8))) short v8s;            // 8 x bf16 (4 VGPRs) MFMA A/B
typedef __attribute__((ext_vector_type(8))) unsigned short u16x8;
typedef __attribute__((ext_vector_type(4))) float v4f;            // MFMA C/D

#define MFMA16(a, b, c) __builtin_amdgcn_mfma_f32_16x16x32_bf16((a), (b), (c), 0, 0, 0)

// async global->LDS, 16B per lane; LDS dest = wave-uniform base + lane*16
#define GLL16(g, l)                                                        \
  __builtin_amdgcn_global_load_lds(                                        \
      (const __attribute__((address_space(1))) unsigned int*)(g),          \
      (__attribute__((address_space(3))) unsigned int*)(l), 16, 0, 0)

#define EXP2F(x) exp2f(x)

__device__ __forceinline__ unsigned short f2bf(float f) {
  union { float f; unsigned u; } v; v.f = f;
  unsigned r = v.u + 0x7fffu + ((v.u >> 16) & 1u);   // RNE
  return (unsigned short)(r >> 16);
}
// truncating pack of two f32 -> bf16x2 (lo in low half)
__device__ __forceinline__ unsigned packbf2(float lo, float hi) {
  union { float f; unsigned u; } a, b; a.f = lo; b.f = hi;
  return (a.u >> 16) | (b.u & 0xffff0000u);
}

// ---------------- fp32 -> bf16 convert (weights) ----------------
__global__ __launch_bounds__(256) void cvt_kernel(const float* __restrict__ in,
                                                  unsigned short* __restrict__ out, int n4) {
  int i = blockIdx.x * 256 + threadIdx.x;
  if (i >= n4) return;
  float4 v = ((const float4*)in)[i];
  ushort4 o;
  o.x = f2bf(v.x); o.y = f2bf(v.y); o.z = f2bf(v.z); o.w = f2bf(v.w);
  ((ushort4*)out)[i] = o;
}

// ---------------- GroupNorm: one block per (b, group); bf16 out [c][l] ----------------
__global__ __launch_bounds__(256) void gn_kernel(const float* __restrict__ x,
                                                 const float* __restrict__ gsc,
                                                 const float* __restrict__ gbi,
                                                 unsigned short* __restrict__ xn) {
  const int b = blockIdx.x >> 5, g = blockIdx.x & 31;
  const float* xp = x + ((size_t)b * 512 + g * 16) * 1024;
  unsigned short* op = xn + ((size_t)b * 512 + g * 16) * 1024;
  const float4* xp4 = (const float4*)xp;

  float s = 0.f, ss = 0.f;
  for (int i = threadIdx.x; i < 4096; i += 256) {
    float4 v = xp4[i];
    s  += (v.x + v.y) + (v.z + v.w);
    ss += (v.x * v.x + v.y * v.y) + (v.z * v.z + v.w * v.w);
  }
  #pragma unroll
  for (int d = 1; d < 64; d <<= 1) { s += __shfl_xor(s, d); ss += __shfl_xor(ss, d); }
  __shared__ float red[2][4];
  const int w = threadIdx.x >> 6;
  if ((threadIdx.x & 63) == 0) { red[0][w] = s; red[1][w] = ss; }
  __syncthreads();
  s  = red[0][0] + red[0][1] + red[0][2] + red[0][3];
  ss = red[1][0] + red[1][1] + red[1][2] + red[1][3];
  const float mu  = s * (1.f / 16384.f);
  const float var = ss * (1.f / 16384.f) - mu * mu;
  const float rs  = rsqrtf(var + 1e-5f);

  for (int i = threadIdx.x; i < 4096; i += 256) {
    float4 v = xp4[i];
    const int c = g * 16 + (i >> 8);
    const float sc = gsc[c] * rs;
    const float bi = gbi[c] - mu * sc;
    ushort4 o;
    o.x = f2bf(v.x * sc + bi); o.y = f2bf(v.y * sc + bi);
    o.z = f2bf(v.z * sc + bi); o.w = f2bf(v.w * sc + bi);
    ((ushort4*)op)[i] = o;
  }
}

// ---------------- bf16 transpose: xn [b][512][1024] -> xnT [b][1024][512] ----------------
__global__ __launch_bounds__(256) void trans_kernel(const unsigned short* __restrict__ src,
                                                    unsigned short* __restrict__ dst) {
  const int b = blockIdx.z, l0 = blockIdx.x * 64, r0 = blockIdx.y * 64;
  const unsigned short* sp = src + (size_t)b * 512 * 1024;
  unsigned short* dp = dst + (size_t)b * 1024 * 512;
  __shared__ unsigned T[64][65];
  const int tid = threadIdx.x;
  const int rr = tid >> 3, c8 = (tid & 7) * 8;
  #pragma unroll
  for (int sw = 0; sw < 2; ++sw) {
    u16x8 v = *(const u16x8*)(sp + (size_t)(r0 + sw * 32 + rr) * 1024 + l0 + c8);
    #pragma unroll
    for (int j = 0; j < 8; ++j) T[sw * 32 + rr][c8 + j] = v[j];
  }
  __syncthreads();
  #pragma unroll
  for (int sw = 0; sw < 2; ++sw) {
    const int ll = sw * 32 + rr;
    u16x8 o;
    #pragma unroll
    for (int j = 0; j < 8; ++j) o[j] = (unsigned short)T[c8 + j][ll];
    *(u16x8*)(dp + (size_t)(l0 + ll) * 512 + r0 + c8) = o;
  }
}

// ---------------- 128x128 MFMA GEMM, BK=64, xor-swizzled 128B LDS rows ----------------
// A: [M][512] bf16 row-major. BT: [batch][1024][512] bf16 ([n][k]).
template <bool QKV>
__global__ __launch_bounds__(256) void gemm_kernel(
    const unsigned short* __restrict__ A,
    const unsigned short* __restrict__ BT,
    const float* __restrict__ bias,
    const float* __restrict__ xres,
    float* __restrict__ outf,
    unsigned short* __restrict__ qT,
    unsigned short* __restrict__ kT,
    unsigned short* __restrict__ vO) {
  constexpr int K = 512;
  const int n0 = blockIdx.x * 128, m0 = blockIdx.y * 128, b = blockIdx.z;
  const unsigned short* Bp = BT + (size_t)b * 1024 * K;

  __shared__ __align__(16) unsigned short As[128][64];   // 128B rows, xor-swizzled chunks
  __shared__ __align__(16) unsigned short Bs[128][64];

  const int tid = threadIdx.x, lane = tid & 63, w = tid >> 6;
  const int quad = lane >> 4, l15 = lane & 15;
  const int wm = (w >> 1) * 64, wn = (w & 1) * 64;
  // staging: lane -> row (lane>>3), phys chunk (lane&7); logical chunk = phys ^ row
  const int srow = lane >> 3;
  const int scol = ((lane & 7) ^ srow) * 8;              // shorts
  // frag reads: logical chunk (h*4+quad) of row with (row&7)==(l15&7)
  const int ck0 = ((quad ^ (l15 & 7)) * 8);
  const int ck1 = ck0 ^ 32;                              // chunk ^4 -> offset ^32 shorts
  const unsigned short* Asf = &As[0][0];
  const unsigned short* Bsf = &Bs[0][0];

  v4f acc[4][4];
  #pragma unroll
  for (int i = 0; i < 4; ++i)
    #pragma unroll
    for (int j = 0; j < 4; ++j) acc[i][j] = (v4f){0.f, 0.f, 0.f, 0.f};

  for (int kk = 0; kk < K; kk += 64) {
    __syncthreads();
    #pragma unroll
    for (int jj = 0; jj < 8; ++jj) {
      const int job = w * 8 + jj;                        // 0..15 A, 16..31 B
      if (job < 16) {
        GLL16(A + (size_t)(m0 + job * 8 + srow) * K + kk + scol, &As[job * 8][0]);
      } else {
        const int j2 = job - 16;
        GLL16(Bp + (size_t)(n0 + j2 * 8 + srow) * K + kk + scol, &Bs[j2 * 8][0]);
      }
    }
    __syncthreads();
    #pragma unroll
    for (int h = 0; h < 2; ++h) {
      const int ck = h ? ck1 : ck0;
      v8s af[4], bf[4];
      #pragma unroll
      for (int mt = 0; mt < 4; ++mt) af[mt] = *(const v8s*)(Asf + (wm + mt * 16 + l15) * 64 + ck);
      #pragma unroll
      for (int nt = 0; nt < 4; ++nt) bf[nt] = *(const v8s*)(Bsf + (wn + nt * 16 + l15) * 64 + ck);
      #pragma unroll
      for (int mt = 0; mt < 4; ++mt)
        #pragma unroll
        for (int nt = 0; nt < 4; ++nt)
          acc[mt][nt] = MFMA16(af[mt], bf[nt], acc[mt][nt]);
    }
  }

  if (QKV) {
    const int bh8 = b * 8;
    const float cs = 0.18033688011112042f;   // 0.125 * log2(e), folded into q
    #pragma unroll
    for (int mt = 0; mt < 4; ++mt) {
      const int m4 = m0 + wm + mt * 16 + quad * 4;
      const int h = m4 / 192;
      const int rr = m4 - h * 192;
      const int part = rr >> 6;                          // 0=q 1=k 2=v
      const int ch = rr & 63;
      const float b0 = bias[m4], b1 = bias[m4 + 1], b2 = bias[m4 + 2], b3 = bias[m4 + 3];
      #pragma unroll
      for (int nt = 0; nt < 4; ++nt) {
        const int n = n0 + wn + nt * 16 + l15;
        v4f a = acc[mt][nt];
        const float v0 = a[0] + b0, v1 = a[1] + b1, v2 = a[2] + b2, v3 = a[3] + b3;
        if (part == 0) {
          ushort4 st4;
          st4.x = f2bf(v0 * cs); st4.y = f2bf(v1 * cs);
          st4.z = f2bf(v2 * cs); st4.w = f2bf(v3 * cs);
          *(ushort4*)(qT + ((size_t)(bh8 + h) * 1024 + n) * 64 + ch) = st4;
        } else if (part == 1) {
          ushort4 st4;
          st4.x = f2bf(v0); st4.y = f2bf(v1); st4.z = f2bf(v2); st4.w = f2bf(v3);
          *(ushort4*)(kT + ((size_t)(bh8 + h) * 1024 + n) * 64 + ch) = st4;
        } else {
          unsigned short* dp = vO + ((size_t)(bh8 + h) * 64 + ch) * 1024 + n;
          dp[0] = f2bf(v0); dp[1024] = f2bf(v1); dp[2048] = f2bf(v2); dp[3072] = f2bf(v3);
        }
      }
    }
  } else {
    #pragma unroll
    for (int mt = 0; mt < 4; ++mt) {
      const int m4 = m0 + wm + mt * 16 + quad * 4;
      const float b0 = bias[m4], b1 = bias[m4 + 1], b2 = bias[m4 + 2], b3 = bias[m4 + 3];
      #pragma unroll
      for (int nt = 0; nt < 4; ++nt) {
        const int n = n0 + wn + nt * 16 + l15;
        const size_t i0 = ((size_t)b * 512 + m4) * 1024 + n;
        outf[i0]        = xres[i0]        + acc[mt][nt][0] + b0;
        outf[i0 + 1024] = xres[i0 + 1024] + acc[mt][nt][1] + b1;
        outf[i0 + 2048] = xres[i0 + 2048] + acc[mt][nt][2] + b2;
        outf[i0 + 3072] = xres[i0 + 3072] + acc[mt][nt][3] + b3;
      }
    }
  }
}

// ---------------- Flash attention: dbuf K/V, one barrier/tile, swizzled LDS --------
// qT/kT: [bh][1024][64] bf16 (q pre-scaled by 0.125*log2e); v: [bh][64][1024] bf16.
__global__ __launch_bounds__(256) void attn_kernel(const unsigned short* __restrict__ qT,
                                                   const unsigned short* __restrict__ kT,
                                                   const unsigned short* __restrict__ vv,
                                                   unsigned short* __restrict__ aT) {
  const int bh = blockIdx.y;
  const int t0 = blockIdx.x * 64;
  const unsigned short* qb = qT + (size_t)bh * 1024 * 64;
  const unsigned short* kb = kT + (size_t)bh * 1024 * 64;
  const unsigned short* vb = vv + (size_t)bh * 64 * 1024;

  __shared__ __align__(16) unsigned short Qs[64][64];      //  8KB [t][k]
  __shared__ __align__(16) unsigned short Ks[2][64][64];   // 16KB [buf][s][k]
  __shared__ __align__(16) unsigned short Vs[2][64][64];   // 16KB [buf][c][s]

  const int tid = threadIdx.x, w = tid >> 6, lane = tid & 63;
  const int quad = lane >> 4, l15 = lane & 15;
  const int srow = lane >> 3;
  const int scol = ((lane & 7) ^ srow) * 8;
  const int ck0 = ((quad ^ (l15 & 7)) * 8);
  const int ck1 = ck0 ^ 32;
  const unsigned short* Qsf = &Qs[0][0];

  // stage Q (8 segs of 8 rows, 2 per wave) + K/V tile 0
  #pragma unroll
  for (int jj = 0; jj < 2; ++jj) {
    const int seg = w * 2 + jj;
    GLL16(qb + (size_t)(t0 + seg * 8 + srow) * 64 + scol, &Qs[seg * 8][0]);
  }
  #pragma unroll
  for (int jj = 0; jj < 4; ++jj) {
    const int job = w * 4 + jj;
    if (job < 8) GLL16(kb + (size_t)(job * 8 + srow) * 64 + scol, &Ks[0][job * 8][0]);
    else         GLL16(vb + (size_t)((job - 8) * 8 + srow) * 1024 + scol, &Vs[0][(job - 8) * 8][0]);
  }

  v4f o[4];
  #pragma unroll
  for (int i = 0; i < 4; ++i) o[i] = (v4f){0.f, 0.f, 0.f, 0.f};
  float m_s = -1e30f, l_s = 0.f;
  const int sl0 = ((((2 * quad) & 3) << 4) | l15);
  const int sl1 = ((((2 * quad + 1) & 3) << 4) | l15);

  v8s qf0, qf1;
  bool qld = false;

  for (int it = 0; it < 16; ++it) {
    __syncthreads();          // drains stage(it) (in flight during compute(it-1))
    if (!qld) {               // Q stable after first barrier
      qf0 = *(const v8s*)(Qsf + (w * 16 + l15) * 64 + ck0);
      qf1 = *(const v8s*)(Qsf + (w * 16 + l15) * 64 + ck1);
      qld = true;
    }
    if (it + 1 < 16) {        // issue stage(it+1) before compute(it)
      const int s1 = (it + 1) * 64, bp1 = (it + 1) & 1;
      #pragma unroll
      for (int jj = 0; jj < 4; ++jj) {
        const int job = w * 4 + jj;
        if (job < 8)
          GLL16(kb + (size_t)(s1 + job * 8 + srow) * 64 + scol, &Ks[bp1][job * 8][0]);
        else
          GLL16(vb + (size_t)((job - 8) * 8 + srow) * 1024 + s1 + scol,
                &Vs[bp1][(job - 8) * 8][0]);
      }
    }
    const unsigned short* Kb = &Ks[it & 1][0][0];
    const unsigned short* Vb = &Vs[it & 1][0][0];

    // S^T(64s x 16t) = K * Q^T
    v4f sa[4];
    #pragma unroll
    for (int st = 0; st < 4; ++st) {
      v8s kf0 = *(const v8s*)(Kb + (st * 16 + l15) * 64 + ck0);
      v8s kf1 = *(const v8s*)(Kb + (st * 16 + l15) * 64 + ck1);
      v4f z = (v4f){0.f, 0.f, 0.f, 0.f};
      z = MFMA16(kf0, qf0, z);
      sa[st] = MFMA16(kf1, qf1, z);
    }

    // online softmax in log2 domain (scale folded into q)
    float mx = -1e30f;
    #pragma unroll
    for (int st = 0; st < 4; ++st)
      #pragma unroll
      for (int r = 0; r < 4; ++r) mx = fmaxf(mx, sa[st][r]);
    mx = fmaxf(mx, __shfl_xor(mx, 16));
    mx = fmaxf(mx, __shfl_xor(mx, 32));
    const float mn = fmaxf(m_s, mx);
    const float alpha = EXP2F(m_s - mn);
    float p[4][4], rsum = 0.f;
    #pragma unroll
    for (int st = 0; st < 4; ++st)
      #pragma unroll
      for (int r = 0; r < 4; ++r) { p[st][r] = EXP2F(sa[st][r] - mn); rsum += p[st][r]; }
    rsum += __shfl_xor(rsum, 16);
    rsum += __shfl_xor(rsum, 32);
    l_s = l_s * alpha + rsum;
    m_s = mn;

    float alq[4];
    #pragma unroll
    for (int r = 0; r < 4; ++r) alq[r] = __shfl(alpha, quad * 4 + r);
    #pragma unroll
    for (int nc = 0; nc < 4; ++nc)
      #pragma unroll
      for (int r = 0; r < 4; ++r) o[nc][r] *= alq[r];

    unsigned pk[4][2];
    #pragma unroll
    for (int st = 0; st < 4; ++st) {
      pk[st][0] = packbf2(p[st][0], p[st][1]);
      pk[st][1] = packbf2(p[st][2], p[st][3]);
    }
    union { v8s v; unsigned u[4]; } pa0, pa1;
    #pragma unroll
    for (int e = 0; e < 4; ++e) {
      const int sl = (e >> 1) ? sl1 : sl0;
      unsigned lo0 = __shfl(pk[0][e & 1], sl);
      unsigned hi0 = __shfl(pk[1][e & 1], sl);
      pa0.u[e] = (quad < 2) ? lo0 : hi0;
      unsigned lo1 = __shfl(pk[2][e & 1], sl);
      unsigned hi1 = __shfl(pk[3][e & 1], sl);
      pa1.u[e] = (quad < 2) ? lo1 : hi1;
    }

    // O(16t x 64c) += P * V^T
    #pragma unroll
    for (int nc = 0; nc < 4; ++nc) {
      v8s vf0 = *(const v8s*)(Vb + (nc * 16 + l15) * 64 + ck0);
      v8s vf1 = *(const v8s*)(Vb + (nc * 16 + l15) * 64 + ck1);
      o[nc] = MFMA16(pa0.v, vf0, o[nc]);
      o[nc] = MFMA16(pa1.v, vf1, o[nc]);
    }
  }

  // write aT[b][t][h*64+c] = O[t][c] / l(t)
  const int b = bh >> 3, h = bh & 7;
  float rl[4];
  #pragma unroll
  for (int r = 0; r < 4; ++r) rl[r] = 1.0f / __shfl(l_s, quad * 4 + r);
  #pragma unroll
  for (int nc = 0; nc < 4; ++nc)
    #pragma unroll
    for (int r = 0; r < 4; ++r) {
      aT[((size_t)b * 1024 + t0 + w * 16 + quad * 4 + r) * 512 + h * 64 + nc * 16 + l15] =
          f2bf(o[nc][r] * rl[r]);
    }
}

extern "C" void kernel_launch(void* const* d_in, const int* in_sizes, int n_in,
                              void* d_out, int out_size, void* d_ws, size_t ws_size,
                              hipStream_t stream) {
  const float* x    = (const float*)d_in[0];
  const float* gsc  = (const float*)d_in[1];
  const float* gbi  = (const float*)d_in[2];
  const float* qkvw = (const float*)d_in[3];
  const float* qkvb = (const float*)d_in[4];
  const float* pjw  = (const float*)d_in[5];
  const float* pjb  = (const float*)d_in[6];
  float* out = (float*)d_out;

  unsigned short* ws  = (unsigned short*)d_ws;
  unsigned short* qw  = ws;                   //  786432  qkv weights bf16
  unsigned short* pw  = qw + 786432;          //  262144  proj weights bf16
  unsigned short* xn  = pw + 262144;          // 4194304  gn out [b][c][l]
  unsigned short* xnT = xn + 4194304;         // 4194304  [b][l][c]
  unsigned short* qT  = xnT + 4194304;        // 4194304  [bh][l][64]
  unsigned short* kT  = qT + 4194304;         // 4194304  [bh][l][64]
  unsigned short* vv  = kT + 4194304;         // 4194304  [bh][64][l]
  unsigned short* aT  = xn;                   // alias (xn dead after transpose)

  cvt_kernel<<<dim3(768), dim3(256), 0, stream>>>(qkvw, qw, 196608);
  cvt_kernel<<<dim3(256), dim3(256), 0, stream>>>(pjw, pw, 65536);
  gn_kernel<<<dim3(256), dim3(256), 0, stream>>>(x, gsc, gbi, xn);
  trans_kernel<<<dim3(16, 8, 8), dim3(256), 0, stream>>>(xn, xnT);
  gemm_kernel<true><<<dim3(8, 12, 8), dim3(256), 0, stream>>>(
      qw, xnT, qkvb, nullptr, nullptr, qT, kT, vv);
  attn_kernel<<<dim3(16, 64), dim3(256), 0, stream>>>(qT, kT, vv, aT);
  gemm_kernel<false><<<dim3(8, 4, 8), dim3(256), 0, stream>>>(
      pw, aT, pjb, x, out, nullptr, nullptr, nullptr);
}

// Round 4
// 157.279 us; speedup vs baseline: 1.7967x; 1.0964x over previous
//
#include <hip/hip_runtime.h>
#include <hip/hip_bf16.h>

typedef __attribute__((ext_vector_type(8))) short v8s;            // 8 x bf16 (4 VGPRs) MFMA A/B
typedef __attribute__((ext_vector_type(8))) unsigned short u16x8;
typedef __attribute__((ext_vector_type(4))) float v4f;            // MFMA C/D

#define MFMA16(a, b, c) __builtin_amdgcn_mfma_f32_16x16x32_bf16((a), (b), (c), 0, 0, 0)

// async global->LDS, 16B per lane; LDS dest = wave-uniform base + lane*16
#define GLL16(g, l)                                                        \
  __builtin_amdgcn_global_load_lds(                                        \
      (const __attribute__((address_space(1))) unsigned int*)(g),          \
      (__attribute__((address_space(3))) unsigned int*)(l), 16, 0, 0)

// native v_exp_f32 (hard requirement: libm exp2f is a multi-op software expansion)
#if __has_builtin(__builtin_amdgcn_exp2f)
__device__ __forceinline__ float exp2n(float x) { return __builtin_amdgcn_exp2f(x); }
#else
__device__ __forceinline__ float exp2n(float x) {
  float r; asm("v_exp_f32 %0, %1" : "=v"(r) : "v"(x)); return r;
}
#endif

__device__ __forceinline__ unsigned short f2bf(float f) {
  union { float f; unsigned u; } v; v.f = f;
  unsigned r = v.u + 0x7fffu + ((v.u >> 16) & 1u);   // RNE
  return (unsigned short)(r >> 16);
}
// truncating pack of two f32 -> bf16x2 (lo in low half)
__device__ __forceinline__ unsigned packbf2(float lo, float hi) {
  union { float f; unsigned u; } a, b; a.f = lo; b.f = hi;
  return (a.u >> 16) | (b.u & 0xffff0000u);
}

// ---------------- fp32 -> bf16 convert (weights) ----------------
__global__ __launch_bounds__(256) void cvt_kernel(const float* __restrict__ in,
                                                  unsigned short* __restrict__ out, int n4) {
  int i = blockIdx.x * 256 + threadIdx.x;
  if (i >= n4) return;
  float4 v = ((const float4*)in)[i];
  ushort4 o;
  o.x = f2bf(v.x); o.y = f2bf(v.y); o.z = f2bf(v.z); o.w = f2bf(v.w);
  ((ushort4*)out)[i] = o;
}

// ---------------- GroupNorm stats: one block per (b, group) -> (mu, rsig) ----------------
__global__ __launch_bounds__(256) void gn_stats_kernel(const float* __restrict__ x,
                                                       float2* __restrict__ stats) {
  const int b = blockIdx.x >> 5, g = blockIdx.x & 31;
  const float4* xp4 = (const float4*)(x + ((size_t)b * 512 + g * 16) * 1024);
  float s = 0.f, ss = 0.f;
  for (int i = threadIdx.x; i < 4096; i += 256) {
    float4 v = xp4[i];
    s  += (v.x + v.y) + (v.z + v.w);
    ss += (v.x * v.x + v.y * v.y) + (v.z * v.z + v.w * v.w);
  }
  #pragma unroll
  for (int d = 1; d < 64; d <<= 1) { s += __shfl_xor(s, d); ss += __shfl_xor(ss, d); }
  __shared__ float red[2][4];
  const int w = threadIdx.x >> 6;
  if ((threadIdx.x & 63) == 0) { red[0][w] = s; red[1][w] = ss; }
  __syncthreads();
  if (threadIdx.x == 0) {
    s  = red[0][0] + red[0][1] + red[0][2] + red[0][3];
    ss = red[1][0] + red[1][1] + red[1][2] + red[1][3];
    const float mu  = s * (1.f / 16384.f);
    const float var = ss * (1.f / 16384.f) - mu * mu;
    stats[blockIdx.x] = make_float2(mu, rsqrtf(var + 1e-5f));
  }
}

// ---------------- GroupNorm normalize + transpose: x[b][c][l] -> xnT[b][l][c] bf16 ----
__global__ __launch_bounds__(256) void gnt_kernel(const float* __restrict__ x,
                                                  const float2* __restrict__ stats,
                                                  const float* __restrict__ gsc,
                                                  const float* __restrict__ gbi,
                                                  unsigned short* __restrict__ xnT) {
  const int b = blockIdx.z, l0 = blockIdx.x * 64, c0 = blockIdx.y * 64;
  const float* sp = x + (size_t)b * 512 * 1024;
  unsigned short* dp = xnT + (size_t)b * 1024 * 512;
  __shared__ unsigned T[64][65];
  const int tid = threadIdx.x;
  const int rr = tid >> 3, c8 = (tid & 7) * 8;
  #pragma unroll
  for (int sw = 0; sw < 2; ++sw) {
    const int c = c0 + sw * 32 + rr;
    const float2 st = stats[b * 32 + (c >> 4)];
    const float sc = gsc[c] * st.y;
    const float bi = gbi[c] - st.x * sc;
    const float4* px = (const float4*)(sp + (size_t)c * 1024 + l0 + c8);
    float4 v0 = px[0], v1 = px[1];
    T[sw * 32 + rr][c8 + 0] = f2bf(v0.x * sc + bi);
    T[sw * 32 + rr][c8 + 1] = f2bf(v0.y * sc + bi);
    T[sw * 32 + rr][c8 + 2] = f2bf(v0.z * sc + bi);
    T[sw * 32 + rr][c8 + 3] = f2bf(v0.w * sc + bi);
    T[sw * 32 + rr][c8 + 4] = f2bf(v1.x * sc + bi);
    T[sw * 32 + rr][c8 + 5] = f2bf(v1.y * sc + bi);
    T[sw * 32 + rr][c8 + 6] = f2bf(v1.z * sc + bi);
    T[sw * 32 + rr][c8 + 7] = f2bf(v1.w * sc + bi);
  }
  __syncthreads();
  #pragma unroll
  for (int sw = 0; sw < 2; ++sw) {
    const int ll = sw * 32 + rr;
    u16x8 o;
    #pragma unroll
    for (int j = 0; j < 8; ++j) o[j] = (unsigned short)T[c8 + j][ll];
    *(u16x8*)(dp + (size_t)(l0 + ll) * 512 + c0 + c8) = o;
  }
}

// ---------------- 128xNT MFMA GEMM, BK=64, xor-swizzled 128B LDS rows ----------------
// A: [M][512] bf16 row-major. BT: [batch][1024][512] bf16 ([n][k]).
template <bool QKV, int NT>
__global__ __launch_bounds__(256) void gemm_kernel(
    const unsigned short* __restrict__ A,
    const unsigned short* __restrict__ BT,
    const float* __restrict__ bias,
    const float* __restrict__ xres,
    float* __restrict__ outf,
    unsigned short* __restrict__ qT,
    unsigned short* __restrict__ kT,
    unsigned short* __restrict__ vO) {
  constexpr int K = 512;
  constexpr int NFR = NT / 32;              // n-frags per wave
  constexpr int NJOB = 16 + NT / 8;         // staging jobs (A:16, B:NT/8)
  const int n0 = blockIdx.x * NT, m0 = blockIdx.y * 128, b = blockIdx.z;
  const unsigned short* Bp = BT + (size_t)b * 1024 * K;

  __shared__ __align__(16) unsigned short As[128][64];
  __shared__ __align__(16) unsigned short Bs[NT][64];

  const int tid = threadIdx.x, lane = tid & 63, w = tid >> 6;
  const int quad = lane >> 4, l15 = lane & 15;
  const int wm = (w >> 1) * 64, wn = (w & 1) * (NT / 2);
  const int srow = lane >> 3;
  const int scol = ((lane & 7) ^ srow) * 8;
  const int ck0 = ((quad ^ (l15 & 7)) * 8);
  const int ck1 = ck0 ^ 32;
  const unsigned short* Asf = &As[0][0];
  const unsigned short* Bsf = &Bs[0][0];

  v4f acc[4][NFR];
  #pragma unroll
  for (int i = 0; i < 4; ++i)
    #pragma unroll
    for (int j = 0; j < NFR; ++j) acc[i][j] = (v4f){0.f, 0.f, 0.f, 0.f};

  for (int kk = 0; kk < K; kk += 64) {
    __syncthreads();
    #pragma unroll
    for (int jj = 0; jj < NJOB / 4; ++jj) {
      const int job = w * (NJOB / 4) + jj;
      if (job < 16) {
        GLL16(A + (size_t)(m0 + job * 8 + srow) * K + kk + scol, &As[job * 8][0]);
      } else {
        const int j2 = job - 16;
        GLL16(Bp + (size_t)(n0 + j2 * 8 + srow) * K + kk + scol, &Bs[j2 * 8][0]);
      }
    }
    __syncthreads();
    #pragma unroll
    for (int h = 0; h < 2; ++h) {
      const int ck = h ? ck1 : ck0;
      v8s af[4], bf[NFR];
      #pragma unroll
      for (int mt = 0; mt < 4; ++mt) af[mt] = *(const v8s*)(Asf + (wm + mt * 16 + l15) * 64 + ck);
      #pragma unroll
      for (int nt = 0; nt < NFR; ++nt) bf[nt] = *(const v8s*)(Bsf + (wn + nt * 16 + l15) * 64 + ck);
      #pragma unroll
      for (int mt = 0; mt < 4; ++mt)
        #pragma unroll
        for (int nt = 0; nt < NFR; ++nt)
          acc[mt][nt] = MFMA16(af[mt], bf[nt], acc[mt][nt]);
    }
  }

  if (QKV) {
    const int bh8 = b * 8;
    const float cs = 0.18033688011112042f;   // 0.125 * log2(e), folded into q
    #pragma unroll
    for (int mt = 0; mt < 4; ++mt) {
      const int m4 = m0 + wm + mt * 16 + quad * 4;
      const int h = m4 / 192;
      const int rr = m4 - h * 192;
      const int part = rr >> 6;                          // 0=q 1=k 2=v
      const int ch = rr & 63;
      const float b0 = bias[m4], b1 = bias[m4 + 1], b2 = bias[m4 + 2], b3 = bias[m4 + 3];
      #pragma unroll
      for (int nt = 0; nt < NFR; ++nt) {
        const int n = n0 + wn + nt * 16 + l15;
        v4f a = acc[mt][nt];
        const float v0 = a[0] + b0, v1 = a[1] + b1, v2 = a[2] + b2, v3 = a[3] + b3;
        if (part == 0) {
          ushort4 st4;
          st4.x = f2bf(v0 * cs); st4.y = f2bf(v1 * cs);
          st4.z = f2bf(v2 * cs); st4.w = f2bf(v3 * cs);
          *(ushort4*)(qT + ((size_t)(bh8 + h) * 1024 + n) * 64 + ch) = st4;
        } else if (part == 1) {
          ushort4 st4;
          st4.x = f2bf(v0); st4.y = f2bf(v1); st4.z = f2bf(v2); st4.w = f2bf(v3);
          *(ushort4*)(kT + ((size_t)(bh8 + h) * 1024 + n) * 64 + ch) = st4;
        } else {
          unsigned short* dp = vO + ((size_t)(bh8 + h) * 64 + ch) * 1024 + n;
          dp[0] = f2bf(v0); dp[1024] = f2bf(v1); dp[2048] = f2bf(v2); dp[3072] = f2bf(v3);
        }
      }
    }
  } else {
    #pragma unroll
    for (int mt = 0; mt < 4; ++mt) {
      const int m4 = m0 + wm + mt * 16 + quad * 4;
      const float b0 = bias[m4], b1 = bias[m4 + 1], b2 = bias[m4 + 2], b3 = bias[m4 + 3];
      #pragma unroll
      for (int nt = 0; nt < NFR; ++nt) {
        const int n = n0 + wn + nt * 16 + l15;
        const size_t i0 = ((size_t)b * 512 + m4) * 1024 + n;
        outf[i0]        = xres[i0]        + acc[mt][nt][0] + b0;
        outf[i0 + 1024] = xres[i0 + 1024] + acc[mt][nt][1] + b1;
        outf[i0 + 2048] = xres[i0 + 2048] + acc[mt][nt][2] + b2;
        outf[i0 + 3072] = xres[i0 + 3072] + acc[mt][nt][3] + b3;
      }
    }
  }
}

// ---------------- Flash attention: 128-query blocks, 32 q/wave, no-max softmax -------
// qT/kT: [bh][1024][64] bf16 (q pre-scaled by 0.125*log2e); v: [bh][64][1024] bf16.
__global__ __launch_bounds__(256) void attn_kernel(const unsigned short* __restrict__ qT,
                                                   const unsigned short* __restrict__ kT,
                                                   const unsigned short* __restrict__ vv,
                                                   unsigned short* __restrict__ aT) {
  const int bh = blockIdx.y;
  const int t0 = blockIdx.x * 128;
  const unsigned short* qb = qT + (size_t)bh * 1024 * 64;
  const unsigned short* kb = kT + (size_t)bh * 1024 * 64;
  const unsigned short* vb = vv + (size_t)bh * 64 * 1024;

  __shared__ __align__(16) unsigned short Qs[128][64];     // 16KB [t][k]
  __shared__ __align__(16) unsigned short Ks[2][64][64];   // 16KB [buf][s][k]
  __shared__ __align__(16) unsigned short Vs[2][64][64];   // 16KB [buf][c][s]

  const int tid = threadIdx.x, w = tid >> 6, lane = tid & 63;
  const int quad = lane >> 4, l15 = lane & 15;
  const int srow = lane >> 3;
  const int scol = ((lane & 7) ^ srow) * 8;
  const int ck0 = ((quad ^ (l15 & 7)) * 8);
  const int ck1 = ck0 ^ 32;
  const unsigned short* Qsf = &Qs[0][0];

  // stage Q (16 segs of 8 rows, 4 per wave) + K/V tile 0
  #pragma unroll
  for (int jj = 0; jj < 4; ++jj) {
    const int seg = w * 4 + jj;
    GLL16(qb + (size_t)(t0 + seg * 8 + srow) * 64 + scol, &Qs[seg * 8][0]);
  }
  #pragma unroll
  for (int jj = 0; jj < 4; ++jj) {
    const int job = w * 4 + jj;
    if (job < 8) GLL16(kb + (size_t)(job * 8 + srow) * 64 + scol, &Ks[0][job * 8][0]);
    else         GLL16(vb + (size_t)((job - 8) * 8 + srow) * 1024 + scol, &Vs[0][(job - 8) * 8][0]);
  }
  __syncthreads();   // Q + tile0 resident

  v8s qf[2][2];
  #pragma unroll
  for (int tg = 0; tg < 2; ++tg) {
    qf[tg][0] = *(const v8s*)(Qsf + (w * 32 + tg * 16 + l15) * 64 + ck0);
    qf[tg][1] = *(const v8s*)(Qsf + (w * 32 + tg * 16 + l15) * 64 + ck1);
  }

  v4f o[2][4];
  #pragma unroll
  for (int tg = 0; tg < 2; ++tg)
    #pragma unroll
    for (int i = 0; i < 4; ++i) o[tg][i] = (v4f){0.f, 0.f, 0.f, 0.f};
  float lsum[2] = {0.f, 0.f};
  const int sl0 = ((((2 * quad) & 3) << 4) | l15);
  const int sl1 = ((((2 * quad + 1) & 3) << 4) | l15);

  for (int it = 0; it < 16; ++it) {
    // prefetch next tile before compute of this one (drained at next barrier)
    if (it + 1 < 16) {
      const int s1 = (it + 1) * 64, bp1 = (it + 1) & 1;
      #pragma unroll
      for (int jj = 0; jj < 4; ++jj) {
        const int job = w * 4 + jj;
        if (job < 8)
          GLL16(kb + (size_t)(s1 + job * 8 + srow) * 64 + scol, &Ks[bp1][job * 8][0]);
        else
          GLL16(vb + (size_t)((job - 8) * 8 + srow) * 1024 + s1 + scol,
                &Vs[bp1][(job - 8) * 8][0]);
      }
    }
    const unsigned short* Kb = &Ks[it & 1][0][0];
    const unsigned short* Vb = &Vs[it & 1][0][0];

    // S^T(64s x 32t) = K * Q^T ; sa[tg][st]: rows s = st*16+quad*4+r, col t = l15
    v4f sa[2][4];
    #pragma unroll
    for (int st = 0; st < 4; ++st) {
      v8s k0 = *(const v8s*)(Kb + (st * 16 + l15) * 64 + ck0);
      v8s k1 = *(const v8s*)(Kb + (st * 16 + l15) * 64 + ck1);
      #pragma unroll
      for (int tg = 0; tg < 2; ++tg) {
        v4f z = (v4f){0.f, 0.f, 0.f, 0.f};
        z = MFMA16(k0, qf[tg][0], z);
        sa[tg][st] = MFMA16(k1, qf[tg][1], z);
      }
    }

    // softmax without max subtraction (scores bounded; scale folded into q)
    union { v8s v; unsigned u[4]; } pa[2][2];
    #pragma unroll
    for (int tg = 0; tg < 2; ++tg) {
      float p[4][4], rsum = 0.f;
      #pragma unroll
      for (int st = 0; st < 4; ++st)
        #pragma unroll
        for (int r = 0; r < 4; ++r) { p[st][r] = exp2n(sa[tg][st][r]); rsum += p[st][r]; }
      lsum[tg] += rsum;
      unsigned pk[4][2];
      #pragma unroll
      for (int st = 0; st < 4; ++st) {
        pk[st][0] = packbf2(p[st][0], p[st][1]);
        pk[st][1] = packbf2(p[st][2], p[st][3]);
      }
      #pragma unroll
      for (int e = 0; e < 4; ++e) {
        const int sl = (e >> 1) ? sl1 : sl0;
        unsigned lo0 = __shfl(pk[0][e & 1], sl);
        unsigned hi0 = __shfl(pk[1][e & 1], sl);
        pa[tg][0].u[e] = (quad < 2) ? lo0 : hi0;
        unsigned lo1 = __shfl(pk[2][e & 1], sl);
        unsigned hi1 = __shfl(pk[3][e & 1], sl);
        pa[tg][1].u[e] = (quad < 2) ? lo1 : hi1;
      }
    }

    // O(32t x 64c) += P * V^T
    #pragma unroll
    for (int nc = 0; nc < 4; ++nc) {
      v8s v0 = *(const v8s*)(Vb + (nc * 16 + l15) * 64 + ck0);
      v8s v1 = *(const v8s*)(Vb + (nc * 16 + l15) * 64 + ck1);
      #pragma unroll
      for (int tg = 0; tg < 2; ++tg) {
        o[tg][nc] = MFMA16(pa[tg][0].v, v0, o[tg][nc]);
        o[tg][nc] = MFMA16(pa[tg][1].v, v1, o[tg][nc]);
      }
    }
    __syncthreads();   // drains prefetch(it+1); buf(it) reads complete
  }

  // final l reduce across quads; write aT[b][t][h*64+c] = O[t][c] / l(t)
  const int b = bh >> 3, h = bh & 7;
  #pragma unroll
  for (int tg = 0; tg < 2; ++tg) {
    lsum[tg] += __shfl_xor(lsum[tg], 16);
    lsum[tg] += __shfl_xor(lsum[tg], 32);
  }
  #pragma unroll
  for (int tg = 0; tg < 2; ++tg) {
    float rl[4];
    #pragma unroll
    for (int r = 0; r < 4; ++r) rl[r] = 1.0f / __shfl(lsum[tg], quad * 4 + r);
    #pragma unroll
    for (int nc = 0; nc < 4; ++nc)
      #pragma unroll
      for (int r = 0; r < 4; ++r) {
        aT[((size_t)b * 1024 + t0 + w * 32 + tg * 16 + quad * 4 + r) * 512 +
           h * 64 + nc * 16 + l15] = f2bf(o[tg][nc][r] * rl[r]);
      }
  }
}

extern "C" void kernel_launch(void* const* d_in, const int* in_sizes, int n_in,
                              void* d_out, int out_size, void* d_ws, size_t ws_size,
                              hipStream_t stream) {
  const float* x    = (const float*)d_in[0];
  const float* gsc  = (const float*)d_in[1];
  const float* gbi  = (const float*)d_in[2];
  const float* qkvw = (const float*)d_in[3];
  const float* qkvb = (const float*)d_in[4];
  const float* pjw  = (const float*)d_in[5];
  const float* pjb  = (const float*)d_in[6];
  float* out = (float*)d_out;

  unsigned short* ws  = (unsigned short*)d_ws;
  unsigned short* qw  = ws;                   //  786432  qkv weights bf16
  unsigned short* pw  = qw + 786432;          //  262144  proj weights bf16
  float2* stats = (float2*)(pw + 262144);     //  256 float2 = 1024 shorts
  unsigned short* xnT = pw + 262144 + 1024;   // 4194304  [b][l][c]
  unsigned short* qT  = xnT + 4194304;        // 4194304  [bh][l][64]
  unsigned short* kT  = qT + 4194304;         // 4194304  [bh][l][64]
  unsigned short* vv  = kT + 4194304;         // 4194304  [bh][64][l]
  unsigned short* aT  = vv + 4194304;         // 4194304  [b][l][c]
  // total 22,021,120 shorts ~= 44.04 MB

  cvt_kernel<<<dim3(768), dim3(256), 0, stream>>>(qkvw, qw, 196608);
  cvt_kernel<<<dim3(256), dim3(256), 0, stream>>>(pjw, pw, 65536);
  gn_stats_kernel<<<dim3(256), dim3(256), 0, stream>>>(x, stats);
  gnt_kernel<<<dim3(16, 8, 8), dim3(256), 0, stream>>>(x, stats, gsc, gbi, xnT);
  gemm_kernel<true, 128><<<dim3(8, 12, 8), dim3(256), 0, stream>>>(
      qw, xnT, qkvb, nullptr, nullptr, qT, kT, vv);
  attn_kernel<<<dim3(8, 64), dim3(256), 0, stream>>>(qT, kT, vv, aT);
  gemm_kernel<false, 64><<<dim3(16, 4, 8), dim3(256), 0, stream>>>(
      pw, aT, pjb, x, out, nullptr, nullptr, nullptr);
}

// Round 5
// 154.993 us; speedup vs baseline: 1.8232x; 1.0147x over previous
//
#include <hip/hip_runtime.h>
#include <hip/hip_bf16.h>

typedef __attribute__((ext_vector_type(8))) short v8s;            // 8 x bf16 (4 VGPRs) MFMA A/B (K=32)
typedef __attribute__((ext_vector_type(4))) short v4s;            // 4 x bf16 (2 VGPRs) MFMA A/B (K=16)
typedef __attribute__((ext_vector_type(8))) unsigned short u16x8;
typedef __attribute__((ext_vector_type(4))) float v4f;            // MFMA C/D

#define MFMA16(a, b, c) __builtin_amdgcn_mfma_f32_16x16x32_bf16((a), (b), (c), 0, 0, 0)

// K=16 bf16 MFMA: A-frag k = quad*4+j matches the 16x16 C-layout row granularity,
// so an S^T C-layout register block is directly a PV A-fragment (no cross-lane ops).
#if __has_builtin(__builtin_amdgcn_mfma_f32_16x16x16_bf16)
#define MFMA16K16(a, b, c) __builtin_amdgcn_mfma_f32_16x16x16_bf16((a), (b), (c), 0, 0, 0)
#elif __has_builtin(__builtin_amdgcn_mfma_f32_16x16x16bf16_1k)
#define MFMA16K16(a, b, c) __builtin_amdgcn_mfma_f32_16x16x16bf16_1k((a), (b), (c), 0, 0, 0)
#else
static __device__ __forceinline__ v4f mfma16k16_asm(v4s a, v4s b, v4f c) {
  v4f d;
  asm("v_mfma_f32_16x16x16_bf16 %0, %1, %2, %3" : "=v"(d) : "v"(a), "v"(b), "v"(c));
  return d;
}
#define MFMA16K16(a, b, c) mfma16k16_asm((a), (b), (c))
#endif

// async global->LDS, 16B per lane; LDS dest = wave-uniform base + lane*16
#define GLL16(g, l)                                                        \
  __builtin_amdgcn_global_load_lds(                                        \
      (const __attribute__((address_space(1))) unsigned int*)(g),          \
      (__attribute__((address_space(3))) unsigned int*)(l), 16, 0, 0)

// native v_exp_f32 (libm exp2f is a multi-op software expansion)
#if __has_builtin(__builtin_amdgcn_exp2f)
__device__ __forceinline__ float exp2n(float x) { return __builtin_amdgcn_exp2f(x); }
#else
__device__ __forceinline__ float exp2n(float x) {
  float r; asm("v_exp_f32 %0, %1" : "=v"(r) : "v"(x)); return r;
}
#endif

__device__ __forceinline__ unsigned short f2bf(float f) {
  union { float f; unsigned u; } v; v.f = f;
  unsigned r = v.u + 0x7fffu + ((v.u >> 16) & 1u);   // RNE
  return (unsigned short)(r >> 16);
}
// truncating pack of two f32 -> bf16x2 (lo in low half)
__device__ __forceinline__ unsigned packbf2(float lo, float hi) {
  union { float f; unsigned u; } a, b; a.f = lo; b.f = hi;
  return (a.u >> 16) | (b.u & 0xffff0000u);
}

// ---------------- fp32 -> bf16 convert (both weight matrices, one dispatch) --------
__global__ __launch_bounds__(256) void cvt_kernel(const float* __restrict__ in0,
                                                  unsigned short* __restrict__ out0,
                                                  const float* __restrict__ in1,
                                                  unsigned short* __restrict__ out1,
                                                  int n0, int n1) {
  int i = blockIdx.x * 256 + threadIdx.x;
  const float* in; unsigned short* out;
  if (i < n0) { in = in0; out = out0; }
  else        { i -= n0; if (i >= n1) return; in = in1; out = out1; }
  float4 v = ((const float4*)in)[i];
  ushort4 o;
  o.x = f2bf(v.x); o.y = f2bf(v.y); o.z = f2bf(v.z); o.w = f2bf(v.w);
  ((ushort4*)out)[i] = o;
}

// ---------------- GroupNorm stats: one block per (b, group) -> (mu, rsig) ----------------
__global__ __launch_bounds__(256) void gn_stats_kernel(const float* __restrict__ x,
                                                       float2* __restrict__ stats) {
  const int b = blockIdx.x >> 5, g = blockIdx.x & 31;
  const float4* xp4 = (const float4*)(x + ((size_t)b * 512 + g * 16) * 1024);
  float s = 0.f, ss = 0.f;
  for (int i = threadIdx.x; i < 4096; i += 256) {
    float4 v = xp4[i];
    s  += (v.x + v.y) + (v.z + v.w);
    ss += (v.x * v.x + v.y * v.y) + (v.z * v.z + v.w * v.w);
  }
  #pragma unroll
  for (int d = 1; d < 64; d <<= 1) { s += __shfl_xor(s, d); ss += __shfl_xor(ss, d); }
  __shared__ float red[2][4];
  const int w = threadIdx.x >> 6;
  if ((threadIdx.x & 63) == 0) { red[0][w] = s; red[1][w] = ss; }
  __syncthreads();
  if (threadIdx.x == 0) {
    s  = red[0][0] + red[0][1] + red[0][2] + red[0][3];
    ss = red[1][0] + red[1][1] + red[1][2] + red[1][3];
    const float mu  = s * (1.f / 16384.f);
    const float var = ss * (1.f / 16384.f) - mu * mu;
    stats[blockIdx.x] = make_float2(mu, rsqrtf(var + 1e-5f));
  }
}

// ---------------- GroupNorm normalize + transpose: x[b][c][l] -> xnT[b][l][c] bf16 ----
__global__ __launch_bounds__(256) void gnt_kernel(const float* __restrict__ x,
                                                  const float2* __restrict__ stats,
                                                  const float* __restrict__ gsc,
                                                  const float* __restrict__ gbi,
                                                  unsigned short* __restrict__ xnT) {
  const int b = blockIdx.z, l0 = blockIdx.x * 64, c0 = blockIdx.y * 64;
  const float* sp = x + (size_t)b * 512 * 1024;
  unsigned short* dp = xnT + (size_t)b * 1024 * 512;
  __shared__ unsigned T[64][65];
  const int tid = threadIdx.x;
  const int rr = tid >> 3, c8 = (tid & 7) * 8;
  #pragma unroll
  for (int sw = 0; sw < 2; ++sw) {
    const int c = c0 + sw * 32 + rr;
    const float2 st = stats[b * 32 + (c >> 4)];
    const float sc = gsc[c] * st.y;
    const float bi = gbi[c] - st.x * sc;
    const float4* px = (const float4*)(sp + (size_t)c * 1024 + l0 + c8);
    float4 v0 = px[0], v1 = px[1];
    T[sw * 32 + rr][c8 + 0] = f2bf(v0.x * sc + bi);
    T[sw * 32 + rr][c8 + 1] = f2bf(v0.y * sc + bi);
    T[sw * 32 + rr][c8 + 2] = f2bf(v0.z * sc + bi);
    T[sw * 32 + rr][c8 + 3] = f2bf(v0.w * sc + bi);
    T[sw * 32 + rr][c8 + 4] = f2bf(v1.x * sc + bi);
    T[sw * 32 + rr][c8 + 5] = f2bf(v1.y * sc + bi);
    T[sw * 32 + rr][c8 + 6] = f2bf(v1.z * sc + bi);
    T[sw * 32 + rr][c8 + 7] = f2bf(v1.w * sc + bi);
  }
  __syncthreads();
  #pragma unroll
  for (int sw = 0; sw < 2; ++sw) {
    const int ll = sw * 32 + rr;
    u16x8 o;
    #pragma unroll
    for (int j = 0; j < 8; ++j) o[j] = (unsigned short)T[c8 + j][ll];
    *(u16x8*)(dp + (size_t)(l0 + ll) * 512 + c0 + c8) = o;
  }
}

// ---------------- 128xNT MFMA GEMM, BK=64, xor-swizzled 128B LDS rows ----------------
// A: [M][512] bf16 row-major. BT: [batch][1024][512] bf16 ([n][k]).
template <bool QKV, int NT>
__global__ __launch_bounds__(256) void gemm_kernel(
    const unsigned short* __restrict__ A,
    const unsigned short* __restrict__ BT,
    const float* __restrict__ bias,
    const float* __restrict__ xres,
    float* __restrict__ outf,
    unsigned short* __restrict__ qT,
    unsigned short* __restrict__ kT,
    unsigned short* __restrict__ vO) {
  constexpr int K = 512;
  constexpr int NFR = NT / 32;              // n-frags per wave
  constexpr int NJOB = 16 + NT / 8;         // staging jobs (A:16, B:NT/8)
  const int n0 = blockIdx.x * NT, m0 = blockIdx.y * 128, b = blockIdx.z;
  const unsigned short* Bp = BT + (size_t)b * 1024 * K;

  __shared__ __align__(16) unsigned short As[128][64];
  __shared__ __align__(16) unsigned short Bs[NT][64];

  const int tid = threadIdx.x, lane = tid & 63, w = tid >> 6;
  const int quad = lane >> 4, l15 = lane & 15;
  const int wm = (w >> 1) * 64, wn = (w & 1) * (NT / 2);
  const int srow = lane >> 3;
  const int scol = ((lane & 7) ^ srow) * 8;
  const int ck0 = ((quad ^ (l15 & 7)) * 8);
  const int ck1 = ck0 ^ 32;
  const unsigned short* Asf = &As[0][0];
  const unsigned short* Bsf = &Bs[0][0];

  v4f acc[4][NFR];
  #pragma unroll
  for (int i = 0; i < 4; ++i)
    #pragma unroll
    for (int j = 0; j < NFR; ++j) acc[i][j] = (v4f){0.f, 0.f, 0.f, 0.f};

  for (int kk = 0; kk < K; kk += 64) {
    __syncthreads();
    #pragma unroll
    for (int jj = 0; jj < NJOB / 4; ++jj) {
      const int job = w * (NJOB / 4) + jj;
      if (job < 16) {
        GLL16(A + (size_t)(m0 + job * 8 + srow) * K + kk + scol, &As[job * 8][0]);
      } else {
        const int j2 = job - 16;
        GLL16(Bp + (size_t)(n0 + j2 * 8 + srow) * K + kk + scol, &Bs[j2 * 8][0]);
      }
    }
    __syncthreads();
    #pragma unroll
    for (int h = 0; h < 2; ++h) {
      const int ck = h ? ck1 : ck0;
      v8s af[4], bf[NFR];
      #pragma unroll
      for (int mt = 0; mt < 4; ++mt) af[mt] = *(const v8s*)(Asf + (wm + mt * 16 + l15) * 64 + ck);
      #pragma unroll
      for (int nt = 0; nt < NFR; ++nt) bf[nt] = *(const v8s*)(Bsf + (wn + nt * 16 + l15) * 64 + ck);
      #pragma unroll
      for (int mt = 0; mt < 4; ++mt)
        #pragma unroll
        for (int nt = 0; nt < NFR; ++nt)
          acc[mt][nt] = MFMA16(af[mt], bf[nt], acc[mt][nt]);
    }
  }

  if (QKV) {
    const int bh8 = b * 8;
    const float cs = 0.18033688011112042f;   // 0.125 * log2(e), folded into q
    #pragma unroll
    for (int mt = 0; mt < 4; ++mt) {
      const int m4 = m0 + wm + mt * 16 + quad * 4;
      const int h = m4 / 192;
      const int rr = m4 - h * 192;
      const int part = rr >> 6;                          // 0=q 1=k 2=v
      const int ch = rr & 63;
      const float b0 = bias[m4], b1 = bias[m4 + 1], b2 = bias[m4 + 2], b3 = bias[m4 + 3];
      #pragma unroll
      for (int nt = 0; nt < NFR; ++nt) {
        const int n = n0 + wn + nt * 16 + l15;
        v4f a = acc[mt][nt];
        const float v0 = a[0] + b0, v1 = a[1] + b1, v2 = a[2] + b2, v3 = a[3] + b3;
        if (part == 0) {
          ushort4 st4;
          st4.x = f2bf(v0 * cs); st4.y = f2bf(v1 * cs);
          st4.z = f2bf(v2 * cs); st4.w = f2bf(v3 * cs);
          *(ushort4*)(qT + ((size_t)(bh8 + h) * 1024 + n) * 64 + ch) = st4;
        } else if (part == 1) {
          ushort4 st4;
          st4.x = f2bf(v0); st4.y = f2bf(v1); st4.z = f2bf(v2); st4.w = f2bf(v3);
          *(ushort4*)(kT + ((size_t)(bh8 + h) * 1024 + n) * 64 + ch) = st4;
        } else {
          unsigned short* dp = vO + ((size_t)(bh8 + h) * 64 + ch) * 1024 + n;
          dp[0] = f2bf(v0); dp[1024] = f2bf(v1); dp[2048] = f2bf(v2); dp[3072] = f2bf(v3);
        }
      }
    }
  } else {
    #pragma unroll
    for (int mt = 0; mt < 4; ++mt) {
      const int m4 = m0 + wm + mt * 16 + quad * 4;
      const float b0 = bias[m4], b1 = bias[m4 + 1], b2 = bias[m4 + 2], b3 = bias[m4 + 3];
      #pragma unroll
      for (int nt = 0; nt < NFR; ++nt) {
        const int n = n0 + wn + nt * 16 + l15;
        const size_t i0 = ((size_t)b * 512 + m4) * 1024 + n;
        outf[i0]        = xres[i0]        + acc[mt][nt][0] + b0;
        outf[i0 + 1024] = xres[i0 + 1024] + acc[mt][nt][1] + b1;
        outf[i0 + 2048] = xres[i0 + 2048] + acc[mt][nt][2] + b2;
        outf[i0 + 3072] = xres[i0 + 3072] + acc[mt][nt][3] + b3;
      }
    }
  }
}

// ---------------- Flash attention: 128-query blocks, 32 q/wave, no-max softmax -------
// qT/kT: [bh][1024][64] bf16 (q pre-scaled by 0.125*log2e); v: [bh][64][1024] bf16.
// PV uses 16x16x16 MFMA so the S^T C-layout is directly the A-fragment (no bpermute).
__global__ __launch_bounds__(256) void attn_kernel(const unsigned short* __restrict__ qT,
                                                   const unsigned short* __restrict__ kT,
                                                   const unsigned short* __restrict__ vv,
                                                   unsigned short* __restrict__ aT) {
  const int bh = blockIdx.y;
  const int t0 = blockIdx.x * 128;
  const unsigned short* qb = qT + (size_t)bh * 1024 * 64;
  const unsigned short* kb = kT + (size_t)bh * 1024 * 64;
  const unsigned short* vb = vv + (size_t)bh * 64 * 1024;

  __shared__ __align__(16) unsigned short Qs[128][64];     // 16KB [t][k]
  __shared__ __align__(16) unsigned short Ks[2][64][64];   // 16KB [buf][s][k]
  __shared__ __align__(16) unsigned short Vs[2][64][64];   // 16KB [buf][c][s]

  const int tid = threadIdx.x, w = tid >> 6, lane = tid & 63;
  const int quad = lane >> 4, l15 = lane & 15;
  const int srow = lane >> 3;
  const int scol = ((lane & 7) ^ srow) * 8;
  const int ck0 = ((quad ^ (l15 & 7)) * 8);
  const int ck1 = ck0 ^ 32;
  const unsigned short* Qsf = &Qs[0][0];

  // stage Q (16 segs of 8 rows, 4 per wave) + K/V tile 0
  #pragma unroll
  for (int jj = 0; jj < 4; ++jj) {
    const int seg = w * 4 + jj;
    GLL16(qb + (size_t)(t0 + seg * 8 + srow) * 64 + scol, &Qs[seg * 8][0]);
  }
  #pragma unroll
  for (int jj = 0; jj < 4; ++jj) {
    const int job = w * 4 + jj;
    if (job < 8) GLL16(kb + (size_t)(job * 8 + srow) * 64 + scol, &Ks[0][job * 8][0]);
    else         GLL16(vb + (size_t)((job - 8) * 8 + srow) * 1024 + scol, &Vs[0][(job - 8) * 8][0]);
  }
  __syncthreads();   // Q + tile0 resident

  v8s qf[2][2];
  #pragma unroll
  for (int tg = 0; tg < 2; ++tg) {
    qf[tg][0] = *(const v8s*)(Qsf + (w * 32 + tg * 16 + l15) * 64 + ck0);
    qf[tg][1] = *(const v8s*)(Qsf + (w * 32 + tg * 16 + l15) * 64 + ck1);
  }

  v4f o[2][4];
  #pragma unroll
  for (int tg = 0; tg < 2; ++tg)
    #pragma unroll
    for (int i = 0; i < 4; ++i) o[tg][i] = (v4f){0.f, 0.f, 0.f, 0.f};
  float lsum[2] = {0.f, 0.f};

  // V B-frag (16x16x16) address pieces: row = nc*16+l15, s = st*16 + quad*4 + i
  const int vq4 = (quad & 1) * 4;          // within-chunk short offset
  const int vqh = quad >> 1;               // chunk parity from quad

  for (int it = 0; it < 16; ++it) {
    // prefetch next tile before compute of this one (drained at next barrier)
    if (it + 1 < 16) {
      const int s1 = (it + 1) * 64, bp1 = (it + 1) & 1;
      #pragma unroll
      for (int jj = 0; jj < 4; ++jj) {
        const int job = w * 4 + jj;
        if (job < 8)
          GLL16(kb + (size_t)(s1 + job * 8 + srow) * 64 + scol, &Ks[bp1][job * 8][0]);
        else
          GLL16(vb + (size_t)((job - 8) * 8 + srow) * 1024 + s1 + scol,
                &Vs[bp1][(job - 8) * 8][0]);
      }
    }
    const unsigned short* Kb = &Ks[it & 1][0][0];
    const unsigned short* Vb = &Vs[it & 1][0][0];

    // S^T(64s x 32t) = K * Q^T ; sa[tg][st]: rows s = st*16+quad*4+r, col t = l15
    v4f sa[2][4];
    #pragma unroll
    for (int st = 0; st < 4; ++st) {
      v8s k0 = *(const v8s*)(Kb + (st * 16 + l15) * 64 + ck0);
      v8s k1 = *(const v8s*)(Kb + (st * 16 + l15) * 64 + ck1);
      #pragma unroll
      for (int tg = 0; tg < 2; ++tg) {
        v4f z = (v4f){0.f, 0.f, 0.f, 0.f};
        z = MFMA16(k0, qf[tg][0], z);
        sa[tg][st] = MFMA16(k1, qf[tg][1], z);
      }
    }

    // softmax without max subtraction (scores bounded; scale folded into q).
    // P stays in C-layout => directly the K=16 A-fragment.
    union { v4s v; unsigned u[2]; } pa[2][4];
    #pragma unroll
    for (int tg = 0; tg < 2; ++tg) {
      float rsum = 0.f;
      #pragma unroll
      for (int st = 0; st < 4; ++st) {
        float p0 = exp2n(sa[tg][st][0]);
        float p1 = exp2n(sa[tg][st][1]);
        float p2 = exp2n(sa[tg][st][2]);
        float p3 = exp2n(sa[tg][st][3]);
        rsum += (p0 + p1) + (p2 + p3);
        pa[tg][st].u[0] = packbf2(p0, p1);
        pa[tg][st].u[1] = packbf2(p2, p3);
      }
      lsum[tg] += rsum;
    }

    // O(32t x 64c) += P * V ; B-frag: V[s=st*16+quad*4+i][c=nc*16+l15] via ds_read_b64
    #pragma unroll
    for (int nc = 0; nc < 4; ++nc) {
      const int row = nc * 16 + l15;
      const unsigned short* vrow = Vb + row * 64 + vq4;
      const int rx = row & 7;
      #pragma unroll
      for (int st = 0; st < 4; ++st) {
        v4s vb4 = *(const v4s*)(vrow + ((st * 2 + vqh) ^ rx) * 8);
        o[0][nc] = MFMA16K16(pa[0][st].v, vb4, o[0][nc]);
        o[1][nc] = MFMA16K16(pa[1][st].v, vb4, o[1][nc]);
      }
    }
    __syncthreads();   // drains prefetch(it+1); buf(it) reads complete
  }

  // final l reduce across quads; write aT[b][t][h*64+c] = O[t][c] / l(t)
  const int b = bh >> 3, h = bh & 7;
  #pragma unroll
  for (int tg = 0; tg < 2; ++tg) {
    lsum[tg] += __shfl_xor(lsum[tg], 16);
    lsum[tg] += __shfl_xor(lsum[tg], 32);
  }
  #pragma unroll
  for (int tg = 0; tg < 2; ++tg) {
    float rl[4];
    #pragma unroll
    for (int r = 0; r < 4; ++r) rl[r] = 1.0f / __shfl(lsum[tg], quad * 4 + r);
    #pragma unroll
    for (int nc = 0; nc < 4; ++nc)
      #pragma unroll
      for (int r = 0; r < 4; ++r) {
        aT[((size_t)b * 1024 + t0 + w * 32 + tg * 16 + quad * 4 + r) * 512 +
           h * 64 + nc * 16 + l15] = f2bf(o[tg][nc][r] * rl[r]);
      }
  }
}

extern "C" void kernel_launch(void* const* d_in, const int* in_sizes, int n_in,
                              void* d_out, int out_size, void* d_ws, size_t ws_size,
                              hipStream_t stream) {
  const float* x    = (const float*)d_in[0];
  const float* gsc  = (const float*)d_in[1];
  const float* gbi  = (const float*)d_in[2];
  const float* qkvw = (const float*)d_in[3];
  const float* qkvb = (const float*)d_in[4];
  const float* pjw  = (const float*)d_in[5];
  const float* pjb  = (const float*)d_in[6];
  float* out = (float*)d_out;

  unsigned short* ws  = (unsigned short*)d_ws;
  unsigned short* qw  = ws;                   //  786432  qkv weights bf16
  unsigned short* pw  = qw + 786432;          //  262144  proj weights bf16
  float2* stats = (float2*)(pw + 262144);     //  256 float2 = 1024 shorts
  unsigned short* xnT = pw + 262144 + 1024;   // 4194304  [b][l][c]
  unsigned short* qT  = xnT + 4194304;        // 4194304  [bh][l][64]
  unsigned short* kT  = qT + 4194304;         // 4194304  [bh][l][64]
  unsigned short* vv  = kT + 4194304;         // 4194304  [bh][64][l]
  unsigned short* aT  = vv + 4194304;         // 4194304  [b][l][c]
  // total ~44.04 MB

  cvt_kernel<<<dim3(1024), dim3(256), 0, stream>>>(qkvw, qw, pjw, pw, 196608, 65536);
  gn_stats_kernel<<<dim3(256), dim3(256), 0, stream>>>(x, stats);
  gnt_kernel<<<dim3(16, 8, 8), dim3(256), 0, stream>>>(x, stats, gsc, gbi, xnT);
  gemm_kernel<true, 128><<<dim3(8, 12, 8), dim3(256), 0, stream>>>(
      qw, xnT, qkvb, nullptr, nullptr, qT, kT, vv);
  attn_kernel<<<dim3(8, 64), dim3(256), 0, stream>>>(qT, kT, vv, aT);
  gemm_kernel<false, 64><<<dim3(16, 4, 8), dim3(256), 0, stream>>>(
      pw, aT, pjb, x, out, nullptr, nullptr, nullptr);
}

// Round 6
// 148.626 us; speedup vs baseline: 1.9013x; 1.0428x over previous
//
#include <hip/hip_runtime.h>
#include <hip/hip_bf16.h>

typedef __attribute__((ext_vector_type(8))) short v8s;            // 8 x bf16 (4 VGPRs) MFMA A/B (K=32)
typedef __attribute__((ext_vector_type(4))) short v4s;            // 4 x bf16 (2 VGPRs) MFMA A/B (K=16)
typedef __attribute__((ext_vector_type(8))) unsigned short u16x8;
typedef __attribute__((ext_vector_type(4))) float v4f;            // MFMA C/D

#define MFMA16(a, b, c) __builtin_amdgcn_mfma_f32_16x16x32_bf16((a), (b), (c), 0, 0, 0)

// K=16 bf16 MFMA: A-frag k = quad*4+j matches the 16x16 C-layout row granularity,
// so an S^T C-layout register block is directly a PV A-fragment (no cross-lane ops).
#if __has_builtin(__builtin_amdgcn_mfma_f32_16x16x16_bf16)
#define MFMA16K16(a, b, c) __builtin_amdgcn_mfma_f32_16x16x16_bf16((a), (b), (c), 0, 0, 0)
#elif __has_builtin(__builtin_amdgcn_mfma_f32_16x16x16bf16_1k)
#define MFMA16K16(a, b, c) __builtin_amdgcn_mfma_f32_16x16x16bf16_1k((a), (b), (c), 0, 0, 0)
#else
static __device__ __forceinline__ v4f mfma16k16_asm(v4s a, v4s b, v4f c) {
  v4f d;
  asm("v_mfma_f32_16x16x16_bf16 %0, %1, %2, %3" : "=v"(d) : "v"(a), "v"(b), "v"(c));
  return d;
}
#define MFMA16K16(a, b, c) mfma16k16_asm((a), (b), (c))
#endif

// async global->LDS, 16B per lane; LDS dest = wave-uniform base + lane*16
#define GLL16(g, l)                                                        \
  __builtin_amdgcn_global_load_lds(                                        \
      (const __attribute__((address_space(1))) unsigned int*)(g),          \
      (__attribute__((address_space(3))) unsigned int*)(l), 16, 0, 0)

// native v_exp_f32 (libm exp2f is a multi-op software expansion)
#if __has_builtin(__builtin_amdgcn_exp2f)
__device__ __forceinline__ float exp2n(float x) { return __builtin_amdgcn_exp2f(x); }
#else
__device__ __forceinline__ float exp2n(float x) {
  float r; asm("v_exp_f32 %0, %1" : "=v"(r) : "v"(x)); return r;
}
#endif

__device__ __forceinline__ unsigned short f2bf(float f) {
  union { float f; unsigned u; } v; v.f = f;
  unsigned r = v.u + 0x7fffu + ((v.u >> 16) & 1u);   // RNE
  return (unsigned short)(r >> 16);
}
// truncating pack of two f32 -> bf16x2 (lo in low half)
__device__ __forceinline__ unsigned packbf2(float lo, float hi) {
  union { float f; unsigned u; } a, b; a.f = lo; b.f = hi;
  return (a.u >> 16) | (b.u & 0xffff0000u);
}

// ---------------- fused: weight fp32->bf16 convert  +  GroupNorm stats ----------------
// blocks [0, 1024): convert qkv_w then proj_w (256 float4 each)
// blocks [1024, 1280): gn stats, one block per (b, group) -> (mu, rsig)
__global__ __launch_bounds__(256) void cvt_gn_kernel(const float* __restrict__ in0,
                                                     unsigned short* __restrict__ out0,
                                                     const float* __restrict__ in1,
                                                     unsigned short* __restrict__ out1,
                                                     int n0, int n1,
                                                     const float* __restrict__ x,
                                                     float2* __restrict__ stats) {
  if (blockIdx.x < 1024) {
    int i = blockIdx.x * 256 + threadIdx.x;
    const float* in; unsigned short* out;
    if (i < n0) { in = in0; out = out0; }
    else        { i -= n0; if (i >= n1) return; in = in1; out = out1; }
    float4 v = ((const float4*)in)[i];
    ushort4 o;
    o.x = f2bf(v.x); o.y = f2bf(v.y); o.z = f2bf(v.z); o.w = f2bf(v.w);
    ((ushort4*)out)[i] = o;
    return;
  }
  const int bg = blockIdx.x - 1024;            // 0..255
  const float4* xp4 = (const float4*)(x + (size_t)bg * 16 * 1024);
  float s = 0.f, ss = 0.f;
  for (int i = threadIdx.x; i < 4096; i += 256) {
    float4 v = xp4[i];
    s  += (v.x + v.y) + (v.z + v.w);
    ss += (v.x * v.x + v.y * v.y) + (v.z * v.z + v.w * v.w);
  }
  #pragma unroll
  for (int d = 1; d < 64; d <<= 1) { s += __shfl_xor(s, d); ss += __shfl_xor(ss, d); }
  __shared__ float red[2][4];
  const int w = threadIdx.x >> 6;
  if ((threadIdx.x & 63) == 0) { red[0][w] = s; red[1][w] = ss; }
  __syncthreads();
  if (threadIdx.x == 0) {
    s  = red[0][0] + red[0][1] + red[0][2] + red[0][3];
    ss = red[1][0] + red[1][1] + red[1][2] + red[1][3];
    const float mu  = s * (1.f / 16384.f);
    const float var = ss * (1.f / 16384.f) - mu * mu;
    stats[bg] = make_float2(mu, rsqrtf(var + 1e-5f));
  }
}

// ---------------- GroupNorm normalize + transpose: x[b][c][l] -> xnT[b][l][c] bf16 ----
__global__ __launch_bounds__(256) void gnt_kernel(const float* __restrict__ x,
                                                  const float2* __restrict__ stats,
                                                  const float* __restrict__ gsc,
                                                  const float* __restrict__ gbi,
                                                  unsigned short* __restrict__ xnT) {
  const int b = blockIdx.z, l0 = blockIdx.x * 64, c0 = blockIdx.y * 64;
  const float* sp = x + (size_t)b * 512 * 1024;
  unsigned short* dp = xnT + (size_t)b * 1024 * 512;
  __shared__ unsigned T[64][65];
  const int tid = threadIdx.x;
  const int rr = tid >> 3, c8 = (tid & 7) * 8;
  #pragma unroll
  for (int sw = 0; sw < 2; ++sw) {
    const int c = c0 + sw * 32 + rr;
    const float2 st = stats[b * 32 + (c >> 4)];
    const float sc = gsc[c] * st.y;
    const float bi = gbi[c] - st.x * sc;
    const float4* px = (const float4*)(sp + (size_t)c * 1024 + l0 + c8);
    float4 v0 = px[0], v1 = px[1];
    T[sw * 32 + rr][c8 + 0] = f2bf(v0.x * sc + bi);
    T[sw * 32 + rr][c8 + 1] = f2bf(v0.y * sc + bi);
    T[sw * 32 + rr][c8 + 2] = f2bf(v0.z * sc + bi);
    T[sw * 32 + rr][c8 + 3] = f2bf(v0.w * sc + bi);
    T[sw * 32 + rr][c8 + 4] = f2bf(v1.x * sc + bi);
    T[sw * 32 + rr][c8 + 5] = f2bf(v1.y * sc + bi);
    T[sw * 32 + rr][c8 + 6] = f2bf(v1.z * sc + bi);
    T[sw * 32 + rr][c8 + 7] = f2bf(v1.w * sc + bi);
  }
  __syncthreads();
  #pragma unroll
  for (int sw = 0; sw < 2; ++sw) {
    const int ll = sw * 32 + rr;
    u16x8 o;
    #pragma unroll
    for (int j = 0; j < 8; ++j) o[j] = (unsigned short)T[c8 + j][ll];
    *(u16x8*)(dp + (size_t)(l0 + ll) * 512 + c0 + c8) = o;
  }
}

// ---------------- 128xNT MFMA GEMM, BK=64, xor-swizzled 128B LDS rows ----------------
// A: [M][512] bf16 row-major. BT: [batch][1024][512] bf16 ([n][k]).
template <bool QKV, int NT>
__global__ __launch_bounds__(256) void gemm_kernel(
    const unsigned short* __restrict__ A,
    const unsigned short* __restrict__ BT,
    const float* __restrict__ bias,
    const float* __restrict__ xres,
    float* __restrict__ outf,
    unsigned short* __restrict__ qT,
    unsigned short* __restrict__ kT,
    unsigned short* __restrict__ vO) {
  constexpr int K = 512;
  constexpr int NFR = NT / 32;              // n-frags per wave
  constexpr int NJOB = 16 + NT / 8;         // staging jobs (A:16, B:NT/8)
  const int n0 = blockIdx.x * NT, m0 = blockIdx.y * 128, b = blockIdx.z;
  const unsigned short* Bp = BT + (size_t)b * 1024 * K;

  __shared__ __align__(16) unsigned short As[128][64];
  __shared__ __align__(16) unsigned short Bs[NT][64];

  const int tid = threadIdx.x, lane = tid & 63, w = tid >> 6;
  const int quad = lane >> 4, l15 = lane & 15;
  const int wm = (w >> 1) * 64, wn = (w & 1) * (NT / 2);
  const int srow = lane >> 3;
  const int scol = ((lane & 7) ^ srow) * 8;
  const int ck0 = ((quad ^ (l15 & 7)) * 8);
  const int ck1 = ck0 ^ 32;
  const unsigned short* Asf = &As[0][0];
  const unsigned short* Bsf = &Bs[0][0];

  v4f acc[4][NFR];
  #pragma unroll
  for (int i = 0; i < 4; ++i)
    #pragma unroll
    for (int j = 0; j < NFR; ++j) acc[i][j] = (v4f){0.f, 0.f, 0.f, 0.f};

  for (int kk = 0; kk < K; kk += 64) {
    __syncthreads();
    #pragma unroll
    for (int jj = 0; jj < NJOB / 4; ++jj) {
      const int job = w * (NJOB / 4) + jj;
      if (job < 16) {
        GLL16(A + (size_t)(m0 + job * 8 + srow) * K + kk + scol, &As[job * 8][0]);
      } else {
        const int j2 = job - 16;
        GLL16(Bp + (size_t)(n0 + j2 * 8 + srow) * K + kk + scol, &Bs[j2 * 8][0]);
      }
    }
    __syncthreads();
    #pragma unroll
    for (int h = 0; h < 2; ++h) {
      const int ck = h ? ck1 : ck0;
      v8s af[4], bf[NFR];
      #pragma unroll
      for (int mt = 0; mt < 4; ++mt) af[mt] = *(const v8s*)(Asf + (wm + mt * 16 + l15) * 64 + ck);
      #pragma unroll
      for (int nt = 0; nt < NFR; ++nt) bf[nt] = *(const v8s*)(Bsf + (wn + nt * 16 + l15) * 64 + ck);
      #pragma unroll
      for (int mt = 0; mt < 4; ++mt)
        #pragma unroll
        for (int nt = 0; nt < NFR; ++nt)
          acc[mt][nt] = MFMA16(af[mt], bf[nt], acc[mt][nt]);
    }
  }

  if (QKV) {
    const int bh8 = b * 8;
    const float cs = 0.18033688011112042f;   // 0.125 * log2(e), folded into q
    #pragma unroll
    for (int mt = 0; mt < 4; ++mt) {
      const int m4 = m0 + wm + mt * 16 + quad * 4;
      const int h = m4 / 192;
      const int rr = m4 - h * 192;
      const int part = rr >> 6;                          // 0=q 1=k 2=v
      const int ch = rr & 63;
      const float b0 = bias[m4], b1 = bias[m4 + 1], b2 = bias[m4 + 2], b3 = bias[m4 + 3];
      #pragma unroll
      for (int nt = 0; nt < NFR; ++nt) {
        const int n = n0 + wn + nt * 16 + l15;
        v4f a = acc[mt][nt];
        const float v0 = a[0] + b0, v1 = a[1] + b1, v2 = a[2] + b2, v3 = a[3] + b3;
        if (part == 0) {
          ushort4 st4;
          st4.x = f2bf(v0 * cs); st4.y = f2bf(v1 * cs);
          st4.z = f2bf(v2 * cs); st4.w = f2bf(v3 * cs);
          *(ushort4*)(qT + ((size_t)(bh8 + h) * 1024 + n) * 64 + ch) = st4;
        } else if (part == 1) {
          ushort4 st4;
          st4.x = f2bf(v0); st4.y = f2bf(v1); st4.z = f2bf(v2); st4.w = f2bf(v3);
          *(ushort4*)(kT + ((size_t)(bh8 + h) * 1024 + n) * 64 + ch) = st4;
        } else {
          unsigned short* dp = vO + ((size_t)(bh8 + h) * 64 + ch) * 1024 + n;
          dp[0] = f2bf(v0); dp[1024] = f2bf(v1); dp[2048] = f2bf(v2); dp[3072] = f2bf(v3);
        }
      }
    }
  } else {
    #pragma unroll
    for (int mt = 0; mt < 4; ++mt) {
      const int m4 = m0 + wm + mt * 16 + quad * 4;
      const float b0 = bias[m4], b1 = bias[m4 + 1], b2 = bias[m4 + 2], b3 = bias[m4 + 3];
      #pragma unroll
      for (int nt = 0; nt < NFR; ++nt) {
        const int n = n0 + wn + nt * 16 + l15;
        const size_t i0 = ((size_t)b * 512 + m4) * 1024 + n;
        outf[i0]        = xres[i0]        + acc[mt][nt][0] + b0;
        outf[i0 + 1024] = xres[i0 + 1024] + acc[mt][nt][1] + b1;
        outf[i0 + 2048] = xres[i0 + 2048] + acc[mt][nt][2] + b2;
        outf[i0 + 3072] = xres[i0 + 3072] + acc[mt][nt][3] + b3;
      }
    }
  }
}

// ---------------- Flash attention: 128-query blocks, 32 q/wave, no-max softmax -------
// qT/kT: [bh][1024][64] bf16 (q pre-scaled by 0.125*log2e); v: [bh][64][1024] bf16.
// grid = (bh, t-tile): linear ID = bh + 64*t, so the 8 t-blocks sharing one head's
// K/V get the same ID mod 8 -> same XCD -> K/V (256 KB/head) served from that XCD's L2.
__global__ __launch_bounds__(256) void attn_kernel(const unsigned short* __restrict__ qT,
                                                   const unsigned short* __restrict__ kT,
                                                   const unsigned short* __restrict__ vv,
                                                   unsigned short* __restrict__ aT) {
  const int bh = blockIdx.x;
  const int t0 = blockIdx.y * 128;
  const unsigned short* qb = qT + (size_t)bh * 1024 * 64;
  const unsigned short* kb = kT + (size_t)bh * 1024 * 64;
  const unsigned short* vb = vv + (size_t)bh * 64 * 1024;

  __shared__ __align__(16) unsigned short Qs[128][64];     // 16KB [t][k]
  __shared__ __align__(16) unsigned short Ks[2][64][64];   // 16KB [buf][s][k]
  __shared__ __align__(16) unsigned short Vs[2][64][64];   // 16KB [buf][c][s]

  const int tid = threadIdx.x, w = tid >> 6, lane = tid & 63;
  const int quad = lane >> 4, l15 = lane & 15;
  const int srow = lane >> 3;
  const int scol = ((lane & 7) ^ srow) * 8;
  const int ck0 = ((quad ^ (l15 & 7)) * 8);
  const int ck1 = ck0 ^ 32;
  const unsigned short* Qsf = &Qs[0][0];

  // per-wave staging sources, hoisted: K-wave jobs walk kb, V-wave jobs walk vb
  const int job = w * 4;                     // 0,4,8,12
  // stage Q (16 segs of 8 rows, 4 per wave) + K/V tile 0
  #pragma unroll
  for (int jj = 0; jj < 4; ++jj) {
    const int seg = w * 4 + jj;
    GLL16(qb + (size_t)(t0 + seg * 8 + srow) * 64 + scol, &Qs[seg * 8][0]);
  }
  #pragma unroll
  for (int jj = 0; jj < 4; ++jj) {
    const int j = job + jj;
    if (j < 8) GLL16(kb + (size_t)(j * 8 + srow) * 64 + scol, &Ks[0][j * 8][0]);
    else       GLL16(vb + (size_t)((j - 8) * 8 + srow) * 1024 + scol, &Vs[0][(j - 8) * 8][0]);
  }
  __syncthreads();   // Q + tile0 resident

  v8s qf[2][2];
  #pragma unroll
  for (int tg = 0; tg < 2; ++tg) {
    qf[tg][0] = *(const v8s*)(Qsf + (w * 32 + tg * 16 + l15) * 64 + ck0);
    qf[tg][1] = *(const v8s*)(Qsf + (w * 32 + tg * 16 + l15) * 64 + ck1);
  }

  v4f o[2][4];
  #pragma unroll
  for (int tg = 0; tg < 2; ++tg)
    #pragma unroll
    for (int i = 0; i < 4; ++i) o[tg][i] = (v4f){0.f, 0.f, 0.f, 0.f};
  float lsum[2] = {0.f, 0.f};

  // V B-frag (16x16x16) address pieces: row = nc*16+l15, s = st*16 + quad*4 + i
  const int vq4 = (quad & 1) * 4;          // within-chunk short offset
  const int vqh = quad >> 1;               // chunk parity from quad

  for (int it = 0; it < 16; ++it) {
    // prefetch next tile before compute of this one (drained at next barrier)
    if (it + 1 < 16) {
      const int s1 = (it + 1) * 64, bp1 = (it + 1) & 1;
      #pragma unroll
      for (int jj = 0; jj < 4; ++jj) {
        const int j = job + jj;
        if (j < 8)
          GLL16(kb + (size_t)(s1 + j * 8 + srow) * 64 + scol, &Ks[bp1][j * 8][0]);
        else
          GLL16(vb + (size_t)((j - 8) * 8 + srow) * 1024 + s1 + scol,
                &Vs[bp1][(j - 8) * 8][0]);
      }
    }
    const unsigned short* Kb = &Ks[it & 1][0][0];
    const unsigned short* Vb = &Vs[it & 1][0][0];

    // S^T(64s x 32t) = K * Q^T ; sa[tg][st]: rows s = st*16+quad*4+r, col t = l15
    v4f sa[2][4];
    #pragma unroll
    for (int st = 0; st < 4; ++st) {
      v8s k0 = *(const v8s*)(Kb + (st * 16 + l15) * 64 + ck0);
      v8s k1 = *(const v8s*)(Kb + (st * 16 + l15) * 64 + ck1);
      #pragma unroll
      for (int tg = 0; tg < 2; ++tg) {
        v4f z = (v4f){0.f, 0.f, 0.f, 0.f};
        z = MFMA16(k0, qf[tg][0], z);
        sa[tg][st] = MFMA16(k1, qf[tg][1], z);
      }
    }

    // softmax without max subtraction (scores bounded; scale folded into q).
    // P stays in C-layout => directly the K=16 A-fragment.
    union { v4s v; unsigned u[2]; } pa[2][4];
    #pragma unroll
    for (int tg = 0; tg < 2; ++tg) {
      float rsum = 0.f;
      #pragma unroll
      for (int st = 0; st < 4; ++st) {
        float p0 = exp2n(sa[tg][st][0]);
        float p1 = exp2n(sa[tg][st][1]);
        float p2 = exp2n(sa[tg][st][2]);
        float p3 = exp2n(sa[tg][st][3]);
        rsum += (p0 + p1) + (p2 + p3);
        pa[tg][st].u[0] = packbf2(p0, p1);
        pa[tg][st].u[1] = packbf2(p2, p3);
      }
      lsum[tg] += rsum;
    }

    // O(32t x 64c) += P * V ; B-frag: V[s=st*16+quad*4+i][c=nc*16+l15] via ds_read_b64
    #pragma unroll
    for (int nc = 0; nc < 4; ++nc) {
      const int row = nc * 16 + l15;
      const unsigned short* vrow = Vb + row * 64 + vq4;
      const int rx = row & 7;
      #pragma unroll
      for (int st = 0; st < 4; ++st) {
        v4s vb4 = *(const v4s*)(vrow + ((st * 2 + vqh) ^ rx) * 8);
        o[0][nc] = MFMA16K16(pa[0][st].v, vb4, o[0][nc]);
        o[1][nc] = MFMA16K16(pa[1][st].v, vb4, o[1][nc]);
      }
    }
    __syncthreads();   // drains prefetch(it+1); buf(it) reads complete
  }

  // final l reduce across quads; write aT[b][t][h*64+c] = O[t][c] / l(t)
  const int b = bh >> 3, h = bh & 7;
  #pragma unroll
  for (int tg = 0; tg < 2; ++tg) {
    lsum[tg] += __shfl_xor(lsum[tg], 16);
    lsum[tg] += __shfl_xor(lsum[tg], 32);
  }
  #pragma unroll
  for (int tg = 0; tg < 2; ++tg) {
    float rl[4];
    #pragma unroll
    for (int r = 0; r < 4; ++r) rl[r] = 1.0f / __shfl(lsum[tg], quad * 4 + r);
    #pragma unroll
    for (int nc = 0; nc < 4; ++nc)
      #pragma unroll
      for (int r = 0; r < 4; ++r) {
        aT[((size_t)b * 1024 + t0 + w * 32 + tg * 16 + quad * 4 + r) * 512 +
           h * 64 + nc * 16 + l15] = f2bf(o[tg][nc][r] * rl[r]);
      }
  }
}

extern "C" void kernel_launch(void* const* d_in, const int* in_sizes, int n_in,
                              void* d_out, int out_size, void* d_ws, size_t ws_size,
                              hipStream_t stream) {
  const float* x    = (const float*)d_in[0];
  const float* gsc  = (const float*)d_in[1];
  const float* gbi  = (const float*)d_in[2];
  const float* qkvw = (const float*)d_in[3];
  const float* qkvb = (const float*)d_in[4];
  const float* pjw  = (const float*)d_in[5];
  const float* pjb  = (const float*)d_in[6];
  float* out = (float*)d_out;

  unsigned short* ws  = (unsigned short*)d_ws;
  unsigned short* qw  = ws;                   //  786432  qkv weights bf16
  unsigned short* pw  = qw + 786432;          //  262144  proj weights bf16
  float2* stats = (float2*)(pw + 262144);     //  256 float2 = 1024 shorts
  unsigned short* xnT = pw + 262144 + 1024;   // 4194304  [b][l][c]
  unsigned short* qT  = xnT + 4194304;        // 4194304  [bh][l][64]
  unsigned short* kT  = qT + 4194304;         // 4194304  [bh][l][64]
  unsigned short* vv  = kT + 4194304;         // 4194304  [bh][64][l]
  unsigned short* aT  = vv + 4194304;         // 4194304  [b][l][c]
  // total ~44.04 MB

  cvt_gn_kernel<<<dim3(1280), dim3(256), 0, stream>>>(qkvw, qw, pjw, pw, 196608, 65536,
                                                      x, stats);
  gnt_kernel<<<dim3(16, 8, 8), dim3(256), 0, stream>>>(x, stats, gsc, gbi, xnT);
  gemm_kernel<true, 128><<<dim3(8, 12, 8), dim3(256), 0, stream>>>(
      qw, xnT, qkvb, nullptr, nullptr, qT, kT, vv);
  attn_kernel<<<dim3(64, 8), dim3(256), 0, stream>>>(qT, kT, vv, aT);
  gemm_kernel<false, 64><<<dim3(16, 4, 8), dim3(256), 0, stream>>>(
      pw, aT, pjb, x, out, nullptr, nullptr, nullptr);
}